// Round 9
// baseline (246.182 us; speedup 1.0000x reference)
//
#include <hip/hip_runtime.h>
#include <cmath>

#define IN_F 256
#define H_F  128
#define N_CLS 64
#define SCAN_CHUNK 2048   // 256 threads * 8 elems
#define EPB 4096          // edges per block in sort kernels
#define MAXBK 400         // max coarse buckets (ceil(100096/256)=391)

typedef __attribute__((ext_vector_type(8))) short bf16x8;
typedef __attribute__((ext_vector_type(4))) float f32x4;

__device__ __forceinline__ ushort f2bf(float x) {
  unsigned b = __builtin_bit_cast(unsigned, x);
  b += 0x7FFF + ((b >> 16) & 1);          // RNE
  return (ushort)(b >> 16);
}

// ---------------- both weight transposes->bf16, one kernel ----------------
__global__ void conv_w(const float* __restrict__ W1, ushort* __restrict__ W1T,
                       const float* __restrict__ W2, ushort* __restrict__ W2T) {
  int i = blockIdx.x * blockDim.x + threadIdx.x;
  if (i < IN_F * H_F) {
    int k = i / H_F, n = i % H_F;
    W1T[n * IN_F + k] = f2bf(W1[i]);
  } else if (i < IN_F * H_F + H_F * N_CLS) {
    int j = i - IN_F * H_F;
    int k = j / N_CLS, n = j % N_CLS;
    W2T[n * H_F + k] = f2bf(W2[j]);
  }
}

// ---------------- graph build: atomic-free two-level counting sort ----------------
__global__ __launch_bounds__(256) void hist_kernel(const int* __restrict__ src,
                                                   const int* __restrict__ dst,
                                                   int* __restrict__ hist,
                                                   int NBK, int NBLK, int E) {
  __shared__ int hD[MAXBK], hS[MAXBK];
  int t = threadIdx.x, blk = blockIdx.x;
  for (int b = t; b < NBK; b += 256) { hD[b] = 0; hS[b] = 0; }
  __syncthreads();
  int e0 = blk * EPB;
#pragma unroll
  for (int j = 0; j < EPB / 256; ++j) {
    int idx = e0 + j * 256 + t;
    if (idx < E) {
      atomicAdd(&hD[dst[idx] >> 8], 1);
      atomicAdd(&hS[src[idx] >> 8], 1);
    }
  }
  __syncthreads();
  for (int b = t; b < NBK; b += 256) {
    hist[(size_t)b * NBLK + blk] = hD[b];
    hist[(size_t)(NBK + b) * NBLK + blk] = hS[b];
  }
}

// exclusive scan of cnt[0..nbk) into pos[0..nbk), nbk <= 512, 256 threads
__device__ void excl_scan_lds(int* cnt, int* pos, int t, int nbk) {
  for (int b = t; b < nbk; b += 256) pos[b] = cnt[b];
  __syncthreads();
  for (int d = 1; d < 256; d <<= 1) {
    int u = (t < nbk && t >= d) ? pos[t - d] : 0;
    __syncthreads();
    if (t < nbk && t >= d) pos[t] += u;
    __syncthreads();
  }
  int m2 = nbk - 256;
  int s0 = (m2 > 0) ? pos[255] : 0;
  for (int d = 1; d < 256; d <<= 1) {
    int u = (m2 > 0 && t < m2 && t >= d) ? pos[256 + t - d] : 0;
    __syncthreads();
    if (m2 > 0 && t < m2 && t >= d) pos[256 + t] += u;
    __syncthreads();
  }
  if (m2 > 0 && t < m2) pos[256 + t] += s0;
  __syncthreads();
  for (int b = t; b < nbk; b += 256) pos[b] -= cnt[b];
  __syncthreads();
}

// pairs packed: (src<<8)|(dst&255); side array carries coarse bucket for writeout.
__global__ __launch_bounds__(256) void scatter_kernel(const int* __restrict__ src,
                                                      const int* __restrict__ dst,
                                                      const int* __restrict__ P,
                                                      int* __restrict__ pairs_pk,
                                                      int* __restrict__ srcs_s,
                                                      int NBK, int NBLK, int E) {
  __shared__ int cnt[MAXBK], pos[MAXBK], cur[MAXBK], gb[MAXBK];
  __shared__ int stage_pk[EPB];
  __shared__ ushort stage_b[EPB];
  int t = threadIdx.x, blk = blockIdx.x;
  int e0 = blk * EPB;
  int ne = E - e0; if (ne > EPB) ne = EPB;

  // ---- D phase ----
  for (int b = t; b < NBK; b += 256) cnt[b] = 0;
  __syncthreads();
#pragma unroll
  for (int j = 0; j < EPB / 256; ++j) {
    int idx = e0 + j * 256 + t;
    if (idx < E) atomicAdd(&cnt[dst[idx] >> 8], 1);
  }
  __syncthreads();
  excl_scan_lds(cnt, pos, t, NBK);
  for (int b = t; b < NBK; b += 256) { cur[b] = pos[b]; gb[b] = P[(size_t)b * NBLK + blk]; }
  __syncthreads();
#pragma unroll
  for (int j = 0; j < EPB / 256; ++j) {
    int idx = e0 + j * 256 + t;
    if (idx < E) {
      int d = dst[idx];
      int r = atomicAdd(&cur[d >> 8], 1);
      stage_pk[r] = (src[idx] << 8) | (d & 255);
      stage_b[r] = (ushort)(d >> 8);
    }
  }
  __syncthreads();
  for (int i = t; i < ne; i += 256) {
    int b = stage_b[i];
    pairs_pk[gb[b] + (i - pos[b])] = stage_pk[i];
  }
  __syncthreads();

  // ---- S phase ----
  for (int b = t; b < NBK; b += 256) cnt[b] = 0;
  __syncthreads();
#pragma unroll
  for (int j = 0; j < EPB / 256; ++j) {
    int idx = e0 + j * 256 + t;
    if (idx < E) atomicAdd(&cnt[src[idx] >> 8], 1);
  }
  __syncthreads();
  excl_scan_lds(cnt, pos, t, NBK);
  for (int b = t; b < NBK; b += 256) {
    cur[b] = pos[b];
    gb[b] = P[(size_t)(NBK + b) * NBLK + blk] - E;
  }
  __syncthreads();
#pragma unroll
  for (int j = 0; j < EPB / 256; ++j) {
    int idx = e0 + j * 256 + t;
    if (idx < E) {
      int s = src[idx];
      int r = atomicAdd(&cur[s >> 8], 1);
      stage_pk[r] = s;
    }
  }
  __syncthreads();
  for (int i = t; i < ne; i += 256) {
    int s = stage_pk[i];
    int b = s >> 8;
    srcs_s[gb[b] + (i - pos[b])] = s;
  }
}

// per-bucket CSR + in-degree norm + out-degree norm (merged). One block per bucket.
__global__ __launch_bounds__(256) void csr_outdeg_bucket(
    const int* __restrict__ pairs_pk, const int* __restrict__ srcs_s,
    const int* __restrict__ P, int* __restrict__ row_off,
    float* __restrict__ norm_d, float* __restrict__ norm_s,
    int* __restrict__ csr, int NBK, int NBLK, int N, int E) {
  __shared__ int cnt[256], pos[256], cur[256];
  int b = blockIdx.x, t = threadIdx.x;
  int node = b * 256 + t;

  // ---- CSR + norm_d from dst-sorted packed pairs ----
  int bstart = P[(size_t)b * NBLK];
  int bend = (b + 1 < NBK) ? P[(size_t)(b + 1) * NBLK] : E;
  cnt[t] = 0;
  __syncthreads();
  for (int i = bstart + t; i < bend; i += 256) atomicAdd(&cnt[pairs_pk[i] & 255], 1);
  __syncthreads();
  pos[t] = cnt[t];
  __syncthreads();
  for (int d = 1; d < 256; d <<= 1) {
    int u = (t >= d) ? pos[t - d] : 0;
    __syncthreads();
    if (t >= d) pos[t] += u;
    __syncthreads();
  }
  int excl = pos[t] - cnt[t];
  if (node < N) {
    row_off[node] = bstart + excl;
    norm_d[node] = cnt[t] > 0 ? rsqrtf((float)cnt[t]) : 0.f;
  }
  if (b == NBK - 1 && t == 255) row_off[N] = E;
  cur[t] = excl;
  __syncthreads();
  for (int i = bstart + t; i < bend; i += 256) {
    int pk = pairs_pk[i];
    int r = atomicAdd(&cur[pk & 255], 1);
    csr[bstart + r] = (int)((unsigned)pk >> 8);
  }
  __syncthreads();

  // ---- norm_s from src-sorted values ----
  size_t SOFF = (size_t)NBK * NBLK;
  int sstart = P[SOFF + (size_t)b * NBLK] - E;
  int send = (b + 1 < NBK) ? P[SOFF + (size_t)(b + 1) * NBLK] - E : E;
  cnt[t] = 0;
  __syncthreads();
  for (int i = sstart + t; i < send; i += 256) atomicAdd(&cnt[srcs_s[i] & 255], 1);
  __syncthreads();
  if (node < N) norm_s[node] = cnt[t] > 0 ? rsqrtf((float)cnt[t]) : 0.f;
}

// ---------------- generic 3-kernel decoupled scan ----------------
__global__ void scan_part(const int* __restrict__ arr, int* __restrict__ bsum, int len) {
  int base = blockIdx.x * SCAN_CHUNK + threadIdx.x * 8;
  int s = 0;
#pragma unroll
  for (int j = 0; j < 8; ++j) {
    int i = base + j;
    if (i < len) s += arr[i];
  }
#pragma unroll
  for (int d = 1; d < 64; d <<= 1) s += __shfl_xor(s, d);
  __shared__ int ws[4];
  int lane = threadIdx.x & 63, w = threadIdx.x >> 6;
  if (lane == 0) ws[w] = s;
  __syncthreads();
  if (threadIdx.x == 0) bsum[blockIdx.x] = ws[0] + ws[1] + ws[2] + ws[3];
}

__global__ __launch_bounds__(1024) void scan_bsum(int* __restrict__ bsum, int nb) {
  __shared__ int sm[1024];
  int t = threadIdx.x;
  sm[t] = (t < nb) ? bsum[t] : 0;
  __syncthreads();
  for (int d = 1; d < 1024; d <<= 1) {
    int v = (t >= d) ? sm[t - d] : 0;
    __syncthreads();
    sm[t] += v;
    __syncthreads();
  }
  if (t < nb) bsum[t] = (t == 0) ? 0 : sm[t - 1];   // exclusive
}

__global__ void scan_final(const int* __restrict__ arr, const int* __restrict__ bsum_ex,
                           int* __restrict__ outp, int len, int total) {
  int base = blockIdx.x * SCAN_CHUNK + threadIdx.x * 8;
  int v[8], pre[8];
  int s = 0;
#pragma unroll
  for (int j = 0; j < 8; ++j) {
    int i = base + j;
    v[j] = (i < len) ? arr[i] : 0;
    pre[j] = s;
    s += v[j];
  }
  int lane = threadIdx.x & 63, w = threadIdx.x >> 6;
  int inc = s;
#pragma unroll
  for (int d = 1; d < 64; d <<= 1) {
    int u = __shfl_up(inc, d);
    if (lane >= d) inc += u;
  }
  __shared__ int wsum[4], woff[4];
  if (lane == 63) wsum[w] = inc;
  __syncthreads();
  if (threadIdx.x == 0) {
    int r = 0;
    for (int q = 0; q < 4; ++q) { woff[q] = r; r += wsum[q]; }
  }
  __syncthreads();
  int ex = (inc - s) + woff[w] + bsum_ex[blockIdx.x];
#pragma unroll
  for (int j = 0; j < 8; ++j) {
    int i = base + j;
    if (i < len) outp[i] = ex + pre[j];
  }
  if (blockIdx.x == 0 && threadIdx.x == 0) outp[len] = total;
}

// ---------------- layer-1 GEMM: f32 A fused-convert, bf16 MFMA, scale, bf16 out ----
__global__ __launch_bounds__(256) void mfma_gemm1(
    const float* __restrict__ A, const ushort* __restrict__ BT,
    const float* __restrict__ scale, ushort* __restrict__ C, int M) {
  constexpr int BM = 128, BN = 128, KTOT = 256, BK = 64, WM = 2, WN = 2;
  constexpr int FM = (BM / WM) / 16;   // 4
  constexpr int FN = (BN / WN) / 16;   // 4
  constexpr int ABYTES = BM * BK * 2;  // 16 KB
  constexpr int BBYTES = BN * BK * 2;  // 16 KB
  __shared__ char lds[ABYTES + BBYTES];
  char* Asm = lds;
  char* Bsm = lds + ABYTES;

  const int tid = threadIdx.x;
  const int lane = tid & 63;
  const int w = tid >> 6;
  const int wm = w / WN, wn = w % WN;
  const int m0 = blockIdx.x * BM;

  f32x4 acc[FM][FN];
#pragma unroll
  for (int m = 0; m < FM; ++m)
#pragma unroll
    for (int n = 0; n < FN; ++n) acc[m][n] = (f32x4){0.f, 0.f, 0.f, 0.f};

  const int ra = lane & 15;
  const int kg = lane >> 4;

  for (int kt = 0; kt < KTOT / BK; ++kt) {
#pragma unroll
    for (int s = 0; s < ABYTES / 4096; ++s) {
      int L = s * 4096 + tid * 16;
      int r = L >> 7;
      int slot = (L >> 4) & 7;
      int gr = m0 + r; if (gr >= M) gr = M - 1;
      const float4* gp = (const float4*)(A + (size_t)gr * KTOT + kt * BK + slot * 8);
      float4 va = gp[0], vb = gp[1];
      bf16x8 o;
      o[0] = (short)f2bf(va.x); o[1] = (short)f2bf(va.y);
      o[2] = (short)f2bf(va.z); o[3] = (short)f2bf(va.w);
      o[4] = (short)f2bf(vb.x); o[5] = (short)f2bf(vb.y);
      o[6] = (short)f2bf(vb.z); o[7] = (short)f2bf(vb.w);
      *(bf16x8*)(Asm + (L ^ ((r & 7) << 4))) = o;
    }
#pragma unroll
    for (int s = 0; s < BBYTES / 4096; ++s) {
      int L = s * 4096 + tid * 16;
      int r = L >> 7;
      int slot = (L >> 4) & 7;
      const char* gp = (const char*)BT + (size_t)r * (KTOT * 2) + kt * (BK * 2)
                     + ((slot * 16) ^ ((r & 7) << 4));
      __builtin_amdgcn_global_load_lds(
          (const __attribute__((address_space(1))) unsigned*)gp,
          (__attribute__((address_space(3))) unsigned*)(Bsm + L), 16, 0, 0);
    }
    __syncthreads();

#pragma unroll
    for (int ks = 0; ks < 2; ++ks) {
      bf16x8 af[FM], bfr[FN];
#pragma unroll
      for (int m = 0; m < FM; ++m) {
        int r = wm * (BM / WM) + m * 16 + ra;
        int cb = ks * 64 + kg * 16;
        af[m] = *(const bf16x8*)(Asm + r * 128 + (cb ^ ((r & 7) << 4)));
      }
#pragma unroll
      for (int n = 0; n < FN; ++n) {
        int c = wn * (BN / WN) + n * 16 + ra;
        int cb = ks * 64 + kg * 16;
        bfr[n] = *(const bf16x8*)(Bsm + c * 128 + (cb ^ ((c & 7) << 4)));
      }
#pragma unroll
      for (int m = 0; m < FM; ++m)
#pragma unroll
        for (int n = 0; n < FN; ++n)
          acc[m][n] = __builtin_amdgcn_mfma_f32_16x16x32_bf16(af[m], bfr[n], acc[m][n], 0, 0, 0);
    }
    __syncthreads();
  }

#pragma unroll
  for (int m = 0; m < FM; ++m) {
#pragma unroll
    for (int j = 0; j < 4; ++j) {
      int rl = wm * (BM / WM) + m * 16 + (lane >> 4) * 4 + j;
      int gr = m0 + rl;
      if (gr < M) {
        float sc = scale[gr];
#pragma unroll
        for (int n = 0; n < FN; ++n) {
          int c = wn * (BN / WN) + n * 16 + (lane & 15);
          C[(size_t)gr * BN + c] = f2bf(acc[m][n][j] * sc);
        }
      }
    }
  }
}

// ---------------- layer-2 GEMM (bf16 A via global_load_lds) ----------------
template<int BM, int BN, int KTOT, int WM, int WN>
__global__ __launch_bounds__(256) void mfma_gemm_scale(
    const ushort* __restrict__ A, const ushort* __restrict__ BT,
    const float* __restrict__ scale, ushort* __restrict__ C, int M) {
  constexpr int BK = 64;
  constexpr int FM = (BM / WM) / 16;
  constexpr int FN = (BN / WN) / 16;
  constexpr int ABYTES = BM * BK * 2;
  constexpr int BBYTES = BN * BK * 2;
  __shared__ char lds[ABYTES + BBYTES];
  char* Asm = lds;
  char* Bsm = lds + ABYTES;

  const int tid = threadIdx.x;
  const int lane = tid & 63;
  const int w = tid >> 6;
  const int wm = w / WN, wn = w % WN;
  const int m0 = blockIdx.x * BM;

  f32x4 acc[FM][FN];
#pragma unroll
  for (int m = 0; m < FM; ++m)
#pragma unroll
    for (int n = 0; n < FN; ++n) acc[m][n] = (f32x4){0.f, 0.f, 0.f, 0.f};

  const int ra = lane & 15;
  const int kg = lane >> 4;

  for (int kt = 0; kt < KTOT / BK; ++kt) {
#pragma unroll
    for (int s = 0; s < ABYTES / 4096; ++s) {
      int L = s * 4096 + tid * 16;
      int r = L >> 7;
      int slot = (L >> 4) & 7;
      int gr = m0 + r; if (gr >= M) gr = M - 1;
      const char* gp = (const char*)A + (size_t)gr * (KTOT * 2) + kt * (BK * 2)
                     + ((slot * 16) ^ ((r & 7) << 4));
      __builtin_amdgcn_global_load_lds(
          (const __attribute__((address_space(1))) unsigned*)gp,
          (__attribute__((address_space(3))) unsigned*)(Asm + L), 16, 0, 0);
    }
#pragma unroll
    for (int s = 0; s < BBYTES / 4096; ++s) {
      int L = s * 4096 + tid * 16;
      int r = L >> 7;
      int slot = (L >> 4) & 7;
      const char* gp = (const char*)BT + (size_t)r * (KTOT * 2) + kt * (BK * 2)
                     + ((slot * 16) ^ ((r & 7) << 4));
      __builtin_amdgcn_global_load_lds(
          (const __attribute__((address_space(1))) unsigned*)gp,
          (__attribute__((address_space(3))) unsigned*)(Bsm + L), 16, 0, 0);
    }
    __syncthreads();

#pragma unroll
    for (int ks = 0; ks < 2; ++ks) {
      bf16x8 af[FM], bfr[FN];
#pragma unroll
      for (int m = 0; m < FM; ++m) {
        int r = wm * (BM / WM) + m * 16 + ra;
        int cb = ks * 64 + kg * 16;
        af[m] = *(const bf16x8*)(Asm + r * 128 + (cb ^ ((r & 7) << 4)));
      }
#pragma unroll
      for (int n = 0; n < FN; ++n) {
        int c = wn * (BN / WN) + n * 16 + ra;
        int cb = ks * 64 + kg * 16;
        bfr[n] = *(const bf16x8*)(Bsm + c * 128 + (cb ^ ((c & 7) << 4)));
      }
#pragma unroll
      for (int m = 0; m < FM; ++m)
#pragma unroll
        for (int n = 0; n < FN; ++n)
          acc[m][n] = __builtin_amdgcn_mfma_f32_16x16x32_bf16(af[m], bfr[n], acc[m][n], 0, 0, 0);
    }
    __syncthreads();
  }

#pragma unroll
  for (int m = 0; m < FM; ++m) {
#pragma unroll
    for (int j = 0; j < 4; ++j) {
      int rl = wm * (BM / WM) + m * 16 + (lane >> 4) * 4 + j;
      int gr = m0 + rl;
      if (gr < M) {
        float sc = scale[gr];
#pragma unroll
        for (int n = 0; n < FN; ++n) {
          int c = wn * (BN / WN) + n * 16 + (lane & 15);
          C[(size_t)gr * BN + c] = f2bf(acc[m][n][j] * sc);
        }
      }
    }
  }
}

// ---------------- gather1, feature-phased: phase ph covers features ph*64..ph*64+63 ----
// Two nodes per wave; per-phase slice of h1 = 12.8 MB (one 128B line per row).
__global__ void gather1_ph(const ushort* __restrict__ h1, const int* __restrict__ off,
                           const int* __restrict__ csr, const float* __restrict__ nd,
                           const float* __restrict__ b1, ushort* __restrict__ x2,
                           int N, int ph) {
  int wv = (blockIdx.x * blockDim.x + threadIdx.x) >> 6;
  int lane = threadIdx.x & 63;
  int grp = lane >> 5;
  int sub = lane & 31;
  int node = wv * 2 + grp;
  if (node >= N) return;
  int lo = off[node], hi = off[node + 1];
  const unsigned* h = (const unsigned*)h1;   // row = 64 uints; phase slice = 32
  int base = ph * 32 + sub;
  float sx = 0.f, sy = 0.f;
#define ACC1(u) { sx += __builtin_bit_cast(float, (u) << 16); \
                  sy += __builtin_bit_cast(float, (u) & 0xFFFF0000u); }
  int j = lo;
  for (; j + 8 <= hi; j += 8) {
    int s0 = csr[j+0], s1 = csr[j+1], s2 = csr[j+2], s3 = csr[j+3];
    int s4 = csr[j+4], s5 = csr[j+5], s6 = csr[j+6], s7 = csr[j+7];
    unsigned u0 = h[(size_t)s0 * 64 + base];
    unsigned u1 = h[(size_t)s1 * 64 + base];
    unsigned u2 = h[(size_t)s2 * 64 + base];
    unsigned u3 = h[(size_t)s3 * 64 + base];
    unsigned u4 = h[(size_t)s4 * 64 + base];
    unsigned u5 = h[(size_t)s5 * 64 + base];
    unsigned u6 = h[(size_t)s6 * 64 + base];
    unsigned u7 = h[(size_t)s7 * 64 + base];
    ACC1(u0) ACC1(u1) ACC1(u2) ACC1(u3) ACC1(u4) ACC1(u5) ACC1(u6) ACC1(u7)
  }
  for (; j < hi; ++j) {
    int s = csr[j];
    unsigned u = h[(size_t)s * 64 + base];
    ACC1(u)
  }
#undef ACC1
  float sc = nd[node];
  float2 bb = ((const float2*)b1)[base];
  float ox = fmaxf(sx * sc + bb.x, 0.f);
  float oy = fmaxf(sy * sc + bb.y, 0.f);
  ushort2 o; o.x = f2bf(ox); o.y = f2bf(oy);
  ((ushort2*)x2)[(size_t)node * 64 + base] = o;
}

// ---------------- gather2 (2 nodes/wave, 16-deep) ----------------
__global__ void gather2(const ushort* __restrict__ h2, const int* __restrict__ off,
                        const int* __restrict__ csr, const float* __restrict__ nd,
                        const float* __restrict__ b2, float* __restrict__ out, int N) {
  int wv = (blockIdx.x * blockDim.x + threadIdx.x) >> 6;
  int lane = threadIdx.x & 63;
  int grp = lane >> 5;
  int sub = lane & 31;
  int node = wv * 2 + grp;
  if (node >= N) return;
  int lo = off[node], hi = off[node + 1];
  const unsigned* h = (const unsigned*)h2;
  float s0f = 0.f, s1f = 0.f;
#define ACC2(u) { s0f += __builtin_bit_cast(float, (u) << 16); \
                  s1f += __builtin_bit_cast(float, (u) & 0xFFFF0000u); }
  int j = lo;
  for (; j + 16 <= hi; j += 16) {
    int i0 = csr[j+0], i1 = csr[j+1], i2 = csr[j+2], i3 = csr[j+3];
    int i4 = csr[j+4], i5 = csr[j+5], i6 = csr[j+6], i7 = csr[j+7];
    int i8 = csr[j+8], i9 = csr[j+9], ia = csr[j+10], ib = csr[j+11];
    int ic = csr[j+12], id = csr[j+13], ie = csr[j+14], if_ = csr[j+15];
    unsigned u0 = h[(size_t)i0 * 32 + sub];
    unsigned u1 = h[(size_t)i1 * 32 + sub];
    unsigned u2 = h[(size_t)i2 * 32 + sub];
    unsigned u3 = h[(size_t)i3 * 32 + sub];
    unsigned u4 = h[(size_t)i4 * 32 + sub];
    unsigned u5 = h[(size_t)i5 * 32 + sub];
    unsigned u6 = h[(size_t)i6 * 32 + sub];
    unsigned u7 = h[(size_t)i7 * 32 + sub];
    unsigned u8 = h[(size_t)i8 * 32 + sub];
    unsigned u9 = h[(size_t)i9 * 32 + sub];
    unsigned ua = h[(size_t)ia * 32 + sub];
    unsigned ub = h[(size_t)ib * 32 + sub];
    unsigned uc = h[(size_t)ic * 32 + sub];
    unsigned ud = h[(size_t)id * 32 + sub];
    unsigned ue = h[(size_t)ie * 32 + sub];
    unsigned uf = h[(size_t)if_ * 32 + sub];
    ACC2(u0) ACC2(u1) ACC2(u2) ACC2(u3) ACC2(u4) ACC2(u5) ACC2(u6) ACC2(u7)
    ACC2(u8) ACC2(u9) ACC2(ua) ACC2(ub) ACC2(uc) ACC2(ud) ACC2(ue) ACC2(uf)
  }
  for (; j + 4 <= hi; j += 4) {
    int i0 = csr[j+0], i1 = csr[j+1], i2 = csr[j+2], i3 = csr[j+3];
    unsigned u0 = h[(size_t)i0 * 32 + sub];
    unsigned u1 = h[(size_t)i1 * 32 + sub];
    unsigned u2 = h[(size_t)i2 * 32 + sub];
    unsigned u3 = h[(size_t)i3 * 32 + sub];
    ACC2(u0) ACC2(u1) ACC2(u2) ACC2(u3)
  }
  for (; j < hi; ++j) {
    int i0 = csr[j];
    unsigned u = h[(size_t)i0 * 32 + sub];
    ACC2(u)
  }
#undef ACC2
  float scn = nd[node];
  float2 bb = ((const float2*)b2)[sub];
  float v0 = s0f * scn + bb.x;
  float v1 = s1f * scn + bb.y;
  float2 o;
  o.x = 1.f / (1.f + expf(-v0));
  o.y = 1.f / (1.f + expf(-v1));
  ((float2*)out)[(size_t)node * 32 + sub] = o;
}

extern "C" void kernel_launch(void* const* d_in, const int* in_sizes, int n_in,
                              void* d_out, int out_size, void* d_ws, size_t ws_size,
                              hipStream_t stream) {
  const float* feat = (const float*)d_in[0];
  const int*   src  = (const int*)d_in[1];
  const int*   dst  = (const int*)d_in[2];
  const float* W1   = (const float*)d_in[3];
  const float* b1   = (const float*)d_in[4];
  const float* W2   = (const float*)d_in[5];
  const float* b2   = (const float*)d_in[6];
  float* out = (float*)d_out;

  const int N = in_sizes[0] / IN_F;   // 100000
  const int E = in_sizes[1];          // 1600000

  const int NBK  = (N + 255) >> 8;            // 391 coarse buckets
  const int NBLK = (E + EPB - 1) / EPB;       // 391 sort blocks
  const int HLEN = 2 * NBK * NBLK;

  size_t off = 0;
  auto alloc = [&](size_t bytes) -> void* {
    void* p = (char*)d_ws + off;
    off = (off + bytes + 255) & ~(size_t)255;
    return p;
  };
  int*    hist    = (int*)alloc((size_t)HLEN * 4);
  int*    P       = (int*)alloc((size_t)(HLEN + 1) * 4);
  int*    bsum    = (int*)alloc((size_t)1024 * 4);
  int*    pairs_pk= (int*)alloc((size_t)E * 4);
  int*    srcs_s  = (int*)alloc((size_t)E * 4);
  float*  norm_s  = (float*)alloc((size_t)N * 4);
  float*  norm_d  = (float*)alloc((size_t)N * 4);
  int*    row_off = (int*)alloc((size_t)(N + 1) * 4);
  int*    csr     = (int*)alloc((size_t)E * 4);
  ushort* w1t     = (ushort*)alloc((size_t)H_F * IN_F * 2);
  ushort* w2t     = (ushort*)alloc((size_t)N_CLS * H_F * 2);
  ushort* h1      = (ushort*)alloc((size_t)N * H_F * 2);
  ushort* x2bf    = (ushort*)alloc((size_t)N * H_F * 2);
  ushort* h2      = (ushort*)alloc((size_t)N * N_CLS * 2);
  (void)ws_size;

  conv_w<<<(IN_F * H_F + H_F * N_CLS + 255) / 256, 256, 0, stream>>>(W1, w1t, W2, w2t);

  // graph build (atomic-free)
  hist_kernel<<<NBLK, 256, 0, stream>>>(src, dst, hist, NBK, NBLK, E);
  const int NBS = (HLEN + SCAN_CHUNK - 1) / SCAN_CHUNK;
  scan_part<<<NBS, 256, 0, stream>>>(hist, bsum, HLEN);
  scan_bsum<<<1, 1024, 0, stream>>>(bsum, NBS);
  scan_final<<<NBS, 256, 0, stream>>>(hist, bsum, P, HLEN, 2 * E);
  scatter_kernel<<<NBLK, 256, 0, stream>>>(src, dst, P, pairs_pk, srcs_s, NBK, NBLK, E);
  csr_outdeg_bucket<<<NBK, 256, 0, stream>>>(pairs_pk, srcs_s, P, row_off,
                                             norm_d, norm_s, csr, NBK, NBLK, N, E);

  // layer 1 (conv fused into GEMM A-stage)
  mfma_gemm1<<<(N + 127) / 128, 256, 0, stream>>>(feat, w1t, norm_s, h1, N);
  int pairs = (N + 1) / 2;
  int gblk = (pairs * 64 + 255) / 256;
  gather1_ph<<<gblk, 256, 0, stream>>>(h1, row_off, csr, norm_d, b1, x2bf, N, 0);
  gather1_ph<<<gblk, 256, 0, stream>>>(h1, row_off, csr, norm_d, b1, x2bf, N, 1);

  // layer 2
  mfma_gemm_scale<128, 64, 128, 2, 2><<<(N + 127) / 128, 256, 0, stream>>>(
      x2bf, w2t, norm_s, h2, N);
  gather2<<<(pairs * 64 + 255) / 256, 256, 0, stream>>>(h2, row_off, csr, norm_d, b2, out, N);
}

// Round 10
// 222.899 us; speedup vs baseline: 1.1045x; 1.1045x over previous
//
#include <hip/hip_runtime.h>
#include <cmath>

#define IN_F 256
#define H_F  128
#define N_CLS 64
#define SCAN_CHUNK 2048   // 256 threads * 8 elems
#define EPB 4096          // edges per block in sort kernels
#define MAXBK 400         // max coarse buckets (ceil(100096/256)=391)

typedef __attribute__((ext_vector_type(8))) short bf16x8;
typedef __attribute__((ext_vector_type(4))) float f32x4;

__device__ __forceinline__ ushort f2bf(float x) {
  unsigned b = __builtin_bit_cast(unsigned, x);
  b += 0x7FFF + ((b >> 16) & 1);          // RNE
  return (ushort)(b >> 16);
}

// ---------------- both weight transposes->bf16, one kernel ----------------
__global__ void conv_w(const float* __restrict__ W1, ushort* __restrict__ W1T,
                       const float* __restrict__ W2, ushort* __restrict__ W2T) {
  int i = blockIdx.x * blockDim.x + threadIdx.x;
  if (i < IN_F * H_F) {
    int k = i / H_F, n = i % H_F;
    W1T[n * IN_F + k] = f2bf(W1[i]);
  } else if (i < IN_F * H_F + H_F * N_CLS) {
    int j = i - IN_F * H_F;
    int k = j / N_CLS, n = j % N_CLS;
    W2T[n * H_F + k] = f2bf(W2[j]);
  }
}

// ---------------- graph build: atomic-free two-level counting sort ----------------
__global__ __launch_bounds__(256) void hist_kernel(const int* __restrict__ src,
                                                   const int* __restrict__ dst,
                                                   int* __restrict__ hist,
                                                   int NBK, int NBLK, int E) {
  __shared__ int hD[MAXBK], hS[MAXBK];
  int t = threadIdx.x, blk = blockIdx.x;
  for (int b = t; b < NBK; b += 256) { hD[b] = 0; hS[b] = 0; }
  __syncthreads();
  int e0 = blk * EPB;
#pragma unroll
  for (int j = 0; j < EPB / 256; ++j) {
    int idx = e0 + j * 256 + t;
    if (idx < E) {
      atomicAdd(&hD[dst[idx] >> 8], 1);
      atomicAdd(&hS[src[idx] >> 8], 1);
    }
  }
  __syncthreads();
  for (int b = t; b < NBK; b += 256) {
    hist[(size_t)b * NBLK + blk] = hD[b];
    hist[(size_t)(NBK + b) * NBLK + blk] = hS[b];
  }
}

// exclusive scan of cnt[0..nbk) into pos[0..nbk), nbk <= 512, 256 threads
__device__ void excl_scan_lds(int* cnt, int* pos, int t, int nbk) {
  for (int b = t; b < nbk; b += 256) pos[b] = cnt[b];
  __syncthreads();
  for (int d = 1; d < 256; d <<= 1) {
    int u = (t < nbk && t >= d) ? pos[t - d] : 0;
    __syncthreads();
    if (t < nbk && t >= d) pos[t] += u;
    __syncthreads();
  }
  int m2 = nbk - 256;
  int s0 = (m2 > 0) ? pos[255] : 0;
  for (int d = 1; d < 256; d <<= 1) {
    int u = (m2 > 0 && t < m2 && t >= d) ? pos[256 + t - d] : 0;
    __syncthreads();
    if (m2 > 0 && t < m2 && t >= d) pos[256 + t] += u;
    __syncthreads();
  }
  if (m2 > 0 && t < m2) pos[256 + t] += s0;
  __syncthreads();
  for (int b = t; b < nbk; b += 256) pos[b] -= cnt[b];
  __syncthreads();
}

// pairs packed: (src<<8)|(dst&255); side array carries coarse bucket for writeout.
__global__ __launch_bounds__(256) void scatter_kernel(const int* __restrict__ src,
                                                      const int* __restrict__ dst,
                                                      const int* __restrict__ P,
                                                      int* __restrict__ pairs_pk,
                                                      int* __restrict__ srcs_s,
                                                      int NBK, int NBLK, int E) {
  __shared__ int cnt[MAXBK], pos[MAXBK], cur[MAXBK], gb[MAXBK];
  __shared__ int stage_pk[EPB];
  __shared__ ushort stage_b[EPB];
  int t = threadIdx.x, blk = blockIdx.x;
  int e0 = blk * EPB;
  int ne = E - e0; if (ne > EPB) ne = EPB;

  // ---- D phase ----
  for (int b = t; b < NBK; b += 256) cnt[b] = 0;
  __syncthreads();
#pragma unroll
  for (int j = 0; j < EPB / 256; ++j) {
    int idx = e0 + j * 256 + t;
    if (idx < E) atomicAdd(&cnt[dst[idx] >> 8], 1);
  }
  __syncthreads();
  excl_scan_lds(cnt, pos, t, NBK);
  for (int b = t; b < NBK; b += 256) { cur[b] = pos[b]; gb[b] = P[(size_t)b * NBLK + blk]; }
  __syncthreads();
#pragma unroll
  for (int j = 0; j < EPB / 256; ++j) {
    int idx = e0 + j * 256 + t;
    if (idx < E) {
      int d = dst[idx];
      int r = atomicAdd(&cur[d >> 8], 1);
      stage_pk[r] = (src[idx] << 8) | (d & 255);
      stage_b[r] = (ushort)(d >> 8);
    }
  }
  __syncthreads();
  for (int i = t; i < ne; i += 256) {
    int b = stage_b[i];
    pairs_pk[gb[b] + (i - pos[b])] = stage_pk[i];
  }
  __syncthreads();

  // ---- S phase ----
  for (int b = t; b < NBK; b += 256) cnt[b] = 0;
  __syncthreads();
#pragma unroll
  for (int j = 0; j < EPB / 256; ++j) {
    int idx = e0 + j * 256 + t;
    if (idx < E) atomicAdd(&cnt[src[idx] >> 8], 1);
  }
  __syncthreads();
  excl_scan_lds(cnt, pos, t, NBK);
  for (int b = t; b < NBK; b += 256) {
    cur[b] = pos[b];
    gb[b] = P[(size_t)(NBK + b) * NBLK + blk] - E;
  }
  __syncthreads();
#pragma unroll
  for (int j = 0; j < EPB / 256; ++j) {
    int idx = e0 + j * 256 + t;
    if (idx < E) {
      int s = src[idx];
      int r = atomicAdd(&cur[s >> 8], 1);
      stage_pk[r] = s;
    }
  }
  __syncthreads();
  for (int i = t; i < ne; i += 256) {
    int s = stage_pk[i];
    int b = s >> 8;
    srcs_s[gb[b] + (i - pos[b])] = s;
  }
}

// per-bucket CSR + in-degree norm + out-degree norm (merged). One block per bucket.
__global__ __launch_bounds__(256) void csr_outdeg_bucket(
    const int* __restrict__ pairs_pk, const int* __restrict__ srcs_s,
    const int* __restrict__ P, int* __restrict__ row_off,
    float* __restrict__ norm_d, float* __restrict__ norm_s,
    int* __restrict__ csr, int NBK, int NBLK, int N, int E) {
  __shared__ int cnt[256], pos[256], cur[256];
  int b = blockIdx.x, t = threadIdx.x;
  int node = b * 256 + t;

  // ---- CSR + norm_d from dst-sorted packed pairs ----
  int bstart = P[(size_t)b * NBLK];
  int bend = (b + 1 < NBK) ? P[(size_t)(b + 1) * NBLK] : E;
  cnt[t] = 0;
  __syncthreads();
  for (int i = bstart + t; i < bend; i += 256) atomicAdd(&cnt[pairs_pk[i] & 255], 1);
  __syncthreads();
  pos[t] = cnt[t];
  __syncthreads();
  for (int d = 1; d < 256; d <<= 1) {
    int u = (t >= d) ? pos[t - d] : 0;
    __syncthreads();
    if (t >= d) pos[t] += u;
    __syncthreads();
  }
  int excl = pos[t] - cnt[t];
  if (node < N) {
    row_off[node] = bstart + excl;
    norm_d[node] = cnt[t] > 0 ? rsqrtf((float)cnt[t]) : 0.f;
  }
  if (b == NBK - 1 && t == 255) row_off[N] = E;
  cur[t] = excl;
  __syncthreads();
  for (int i = bstart + t; i < bend; i += 256) {
    int pk = pairs_pk[i];
    int r = atomicAdd(&cur[pk & 255], 1);
    csr[bstart + r] = (int)((unsigned)pk >> 8);
  }
  __syncthreads();

  // ---- norm_s from src-sorted values ----
  size_t SOFF = (size_t)NBK * NBLK;
  int sstart = P[SOFF + (size_t)b * NBLK] - E;
  int send = (b + 1 < NBK) ? P[SOFF + (size_t)(b + 1) * NBLK] - E : E;
  cnt[t] = 0;
  __syncthreads();
  for (int i = sstart + t; i < send; i += 256) atomicAdd(&cnt[srcs_s[i] & 255], 1);
  __syncthreads();
  if (node < N) norm_s[node] = cnt[t] > 0 ? rsqrtf((float)cnt[t]) : 0.f;
}

// ---------------- generic 3-kernel decoupled scan ----------------
__global__ void scan_part(const int* __restrict__ arr, int* __restrict__ bsum, int len) {
  int base = blockIdx.x * SCAN_CHUNK + threadIdx.x * 8;
  int s = 0;
#pragma unroll
  for (int j = 0; j < 8; ++j) {
    int i = base + j;
    if (i < len) s += arr[i];
  }
#pragma unroll
  for (int d = 1; d < 64; d <<= 1) s += __shfl_xor(s, d);
  __shared__ int ws[4];
  int lane = threadIdx.x & 63, w = threadIdx.x >> 6;
  if (lane == 0) ws[w] = s;
  __syncthreads();
  if (threadIdx.x == 0) bsum[blockIdx.x] = ws[0] + ws[1] + ws[2] + ws[3];
}

__global__ __launch_bounds__(1024) void scan_bsum(int* __restrict__ bsum, int nb) {
  __shared__ int sm[1024];
  int t = threadIdx.x;
  sm[t] = (t < nb) ? bsum[t] : 0;
  __syncthreads();
  for (int d = 1; d < 1024; d <<= 1) {
    int v = (t >= d) ? sm[t - d] : 0;
    __syncthreads();
    sm[t] += v;
    __syncthreads();
  }
  if (t < nb) bsum[t] = (t == 0) ? 0 : sm[t - 1];   // exclusive
}

__global__ void scan_final(const int* __restrict__ arr, const int* __restrict__ bsum_ex,
                           int* __restrict__ outp, int len, int total) {
  int base = blockIdx.x * SCAN_CHUNK + threadIdx.x * 8;
  int v[8], pre[8];
  int s = 0;
#pragma unroll
  for (int j = 0; j < 8; ++j) {
    int i = base + j;
    v[j] = (i < len) ? arr[i] : 0;
    pre[j] = s;
    s += v[j];
  }
  int lane = threadIdx.x & 63, w = threadIdx.x >> 6;
  int inc = s;
#pragma unroll
  for (int d = 1; d < 64; d <<= 1) {
    int u = __shfl_up(inc, d);
    if (lane >= d) inc += u;
  }
  __shared__ int wsum[4], woff[4];
  if (lane == 63) wsum[w] = inc;
  __syncthreads();
  if (threadIdx.x == 0) {
    int r = 0;
    for (int q = 0; q < 4; ++q) { woff[q] = r; r += wsum[q]; }
  }
  __syncthreads();
  int ex = (inc - s) + woff[w] + bsum_ex[blockIdx.x];
#pragma unroll
  for (int j = 0; j < 8; ++j) {
    int i = base + j;
    if (i < len) outp[i] = ex + pre[j];
  }
  if (blockIdx.x == 0 && threadIdx.x == 0) outp[len] = total;
}

// ---------------- layer-1 GEMM: f32 A fused-convert, bf16 MFMA, scale, bf16 out ----
__global__ __launch_bounds__(256) void mfma_gemm1(
    const float* __restrict__ A, const ushort* __restrict__ BT,
    const float* __restrict__ scale, ushort* __restrict__ C, int M) {
  constexpr int BM = 128, BN = 128, KTOT = 256, BK = 64, WM = 2, WN = 2;
  constexpr int FM = (BM / WM) / 16;   // 4
  constexpr int FN = (BN / WN) / 16;   // 4
  constexpr int ABYTES = BM * BK * 2;  // 16 KB
  constexpr int BBYTES = BN * BK * 2;  // 16 KB
  __shared__ char lds[ABYTES + BBYTES];
  char* Asm = lds;
  char* Bsm = lds + ABYTES;

  const int tid = threadIdx.x;
  const int lane = tid & 63;
  const int w = tid >> 6;
  const int wm = w / WN, wn = w % WN;
  const int m0 = blockIdx.x * BM;

  f32x4 acc[FM][FN];
#pragma unroll
  for (int m = 0; m < FM; ++m)
#pragma unroll
    for (int n = 0; n < FN; ++n) acc[m][n] = (f32x4){0.f, 0.f, 0.f, 0.f};

  const int ra = lane & 15;
  const int kg = lane >> 4;

  for (int kt = 0; kt < KTOT / BK; ++kt) {
#pragma unroll
    for (int s = 0; s < ABYTES / 4096; ++s) {
      int L = s * 4096 + tid * 16;
      int r = L >> 7;
      int slot = (L >> 4) & 7;
      int gr = m0 + r; if (gr >= M) gr = M - 1;
      const float4* gp = (const float4*)(A + (size_t)gr * KTOT + kt * BK + slot * 8);
      float4 va = gp[0], vb = gp[1];
      bf16x8 o;
      o[0] = (short)f2bf(va.x); o[1] = (short)f2bf(va.y);
      o[2] = (short)f2bf(va.z); o[3] = (short)f2bf(va.w);
      o[4] = (short)f2bf(vb.x); o[5] = (short)f2bf(vb.y);
      o[6] = (short)f2bf(vb.z); o[7] = (short)f2bf(vb.w);
      *(bf16x8*)(Asm + (L ^ ((r & 7) << 4))) = o;
    }
#pragma unroll
    for (int s = 0; s < BBYTES / 4096; ++s) {
      int L = s * 4096 + tid * 16;
      int r = L >> 7;
      int slot = (L >> 4) & 7;
      const char* gp = (const char*)BT + (size_t)r * (KTOT * 2) + kt * (BK * 2)
                     + ((slot * 16) ^ ((r & 7) << 4));
      __builtin_amdgcn_global_load_lds(
          (const __attribute__((address_space(1))) unsigned*)gp,
          (__attribute__((address_space(3))) unsigned*)(Bsm + L), 16, 0, 0);
    }
    __syncthreads();

#pragma unroll
    for (int ks = 0; ks < 2; ++ks) {
      bf16x8 af[FM], bfr[FN];
#pragma unroll
      for (int m = 0; m < FM; ++m) {
        int r = wm * (BM / WM) + m * 16 + ra;
        int cb = ks * 64 + kg * 16;
        af[m] = *(const bf16x8*)(Asm + r * 128 + (cb ^ ((r & 7) << 4)));
      }
#pragma unroll
      for (int n = 0; n < FN; ++n) {
        int c = wn * (BN / WN) + n * 16 + ra;
        int cb = ks * 64 + kg * 16;
        bfr[n] = *(const bf16x8*)(Bsm + c * 128 + (cb ^ ((c & 7) << 4)));
      }
#pragma unroll
      for (int m = 0; m < FM; ++m)
#pragma unroll
        for (int n = 0; n < FN; ++n)
          acc[m][n] = __builtin_amdgcn_mfma_f32_16x16x32_bf16(af[m], bfr[n], acc[m][n], 0, 0, 0);
    }
    __syncthreads();
  }

#pragma unroll
  for (int m = 0; m < FM; ++m) {
#pragma unroll
    for (int j = 0; j < 4; ++j) {
      int rl = wm * (BM / WM) + m * 16 + (lane >> 4) * 4 + j;
      int gr = m0 + rl;
      if (gr < M) {
        float sc = scale[gr];
#pragma unroll
        for (int n = 0; n < FN; ++n) {
          int c = wn * (BN / WN) + n * 16 + (lane & 15);
          C[(size_t)gr * BN + c] = f2bf(acc[m][n][j] * sc);
        }
      }
    }
  }
}

// ---------------- layer-2 GEMM (bf16 A via global_load_lds) ----------------
template<int BM, int BN, int KTOT, int WM, int WN>
__global__ __launch_bounds__(256) void mfma_gemm_scale(
    const ushort* __restrict__ A, const ushort* __restrict__ BT,
    const float* __restrict__ scale, ushort* __restrict__ C, int M) {
  constexpr int BK = 64;
  constexpr int FM = (BM / WM) / 16;
  constexpr int FN = (BN / WN) / 16;
  constexpr int ABYTES = BM * BK * 2;
  constexpr int BBYTES = BN * BK * 2;
  __shared__ char lds[ABYTES + BBYTES];
  char* Asm = lds;
  char* Bsm = lds + ABYTES;

  const int tid = threadIdx.x;
  const int lane = tid & 63;
  const int w = tid >> 6;
  const int wm = w / WN, wn = w % WN;
  const int m0 = blockIdx.x * BM;

  f32x4 acc[FM][FN];
#pragma unroll
  for (int m = 0; m < FM; ++m)
#pragma unroll
    for (int n = 0; n < FN; ++n) acc[m][n] = (f32x4){0.f, 0.f, 0.f, 0.f};

  const int ra = lane & 15;
  const int kg = lane >> 4;

  for (int kt = 0; kt < KTOT / BK; ++kt) {
#pragma unroll
    for (int s = 0; s < ABYTES / 4096; ++s) {
      int L = s * 4096 + tid * 16;
      int r = L >> 7;
      int slot = (L >> 4) & 7;
      int gr = m0 + r; if (gr >= M) gr = M - 1;
      const char* gp = (const char*)A + (size_t)gr * (KTOT * 2) + kt * (BK * 2)
                     + ((slot * 16) ^ ((r & 7) << 4));
      __builtin_amdgcn_global_load_lds(
          (const __attribute__((address_space(1))) unsigned*)gp,
          (__attribute__((address_space(3))) unsigned*)(Asm + L), 16, 0, 0);
    }
#pragma unroll
    for (int s = 0; s < BBYTES / 4096; ++s) {
      int L = s * 4096 + tid * 16;
      int r = L >> 7;
      int slot = (L >> 4) & 7;
      const char* gp = (const char*)BT + (size_t)r * (KTOT * 2) + kt * (BK * 2)
                     + ((slot * 16) ^ ((r & 7) << 4));
      __builtin_amdgcn_global_load_lds(
          (const __attribute__((address_space(1))) unsigned*)gp,
          (__attribute__((address_space(3))) unsigned*)(Bsm + L), 16, 0, 0);
    }
    __syncthreads();

#pragma unroll
    for (int ks = 0; ks < 2; ++ks) {
      bf16x8 af[FM], bfr[FN];
#pragma unroll
      for (int m = 0; m < FM; ++m) {
        int r = wm * (BM / WM) + m * 16 + ra;
        int cb = ks * 64 + kg * 16;
        af[m] = *(const bf16x8*)(Asm + r * 128 + (cb ^ ((r & 7) << 4)));
      }
#pragma unroll
      for (int n = 0; n < FN; ++n) {
        int c = wn * (BN / WN) + n * 16 + ra;
        int cb = ks * 64 + kg * 16;
        bfr[n] = *(const bf16x8*)(Bsm + c * 128 + (cb ^ ((c & 7) << 4)));
      }
#pragma unroll
      for (int m = 0; m < FM; ++m)
#pragma unroll
        for (int n = 0; n < FN; ++n)
          acc[m][n] = __builtin_amdgcn_mfma_f32_16x16x32_bf16(af[m], bfr[n], acc[m][n], 0, 0, 0);
    }
    __syncthreads();
  }

#pragma unroll
  for (int m = 0; m < FM; ++m) {
#pragma unroll
    for (int j = 0; j < 4; ++j) {
      int rl = wm * (BM / WM) + m * 16 + (lane >> 4) * 4 + j;
      int gr = m0 + rl;
      if (gr < M) {
        float sc = scale[gr];
#pragma unroll
        for (int n = 0; n < FN; ++n) {
          int c = wn * (BN / WN) + n * 16 + (lane & 15);
          C[(size_t)gr * BN + c] = f2bf(acc[m][n][j] * sc);
        }
      }
    }
  }
}

// ---------------- gather1 (1 node/wave, 16-deep MLP unroll) ----------------
__global__ void gather1(const ushort* __restrict__ h1, const int* __restrict__ off,
                        const int* __restrict__ csr, const float* __restrict__ nd,
                        const float* __restrict__ b1, ushort* __restrict__ x2, int N) {
  int w = (blockIdx.x * blockDim.x + threadIdx.x) >> 6;
  int lane = threadIdx.x & 63;
  if (w >= N) return;
  int lo = off[w], hi = off[w + 1];
  const unsigned* h = (const unsigned*)h1;
  float sx = 0.f, sy = 0.f;
#define ACC1(u) { sx += __builtin_bit_cast(float, (u) << 16); \
                  sy += __builtin_bit_cast(float, (u) & 0xFFFF0000u); }
  int j = lo;
  for (; j + 16 <= hi; j += 16) {
    int s0 = csr[j+0], s1 = csr[j+1], s2 = csr[j+2], s3 = csr[j+3];
    int s4 = csr[j+4], s5 = csr[j+5], s6 = csr[j+6], s7 = csr[j+7];
    int s8 = csr[j+8], s9 = csr[j+9], sa = csr[j+10], sb = csr[j+11];
    int sc_ = csr[j+12], sd = csr[j+13], se = csr[j+14], sf = csr[j+15];
    unsigned u0 = h[(size_t)s0 * 64 + lane];
    unsigned u1 = h[(size_t)s1 * 64 + lane];
    unsigned u2 = h[(size_t)s2 * 64 + lane];
    unsigned u3 = h[(size_t)s3 * 64 + lane];
    unsigned u4 = h[(size_t)s4 * 64 + lane];
    unsigned u5 = h[(size_t)s5 * 64 + lane];
    unsigned u6 = h[(size_t)s6 * 64 + lane];
    unsigned u7 = h[(size_t)s7 * 64 + lane];
    unsigned u8 = h[(size_t)s8 * 64 + lane];
    unsigned u9 = h[(size_t)s9 * 64 + lane];
    unsigned ua = h[(size_t)sa * 64 + lane];
    unsigned ub = h[(size_t)sb * 64 + lane];
    unsigned uc = h[(size_t)sc_ * 64 + lane];
    unsigned ud = h[(size_t)sd * 64 + lane];
    unsigned ue = h[(size_t)se * 64 + lane];
    unsigned uf = h[(size_t)sf * 64 + lane];
    ACC1(u0) ACC1(u1) ACC1(u2) ACC1(u3) ACC1(u4) ACC1(u5) ACC1(u6) ACC1(u7)
    ACC1(u8) ACC1(u9) ACC1(ua) ACC1(ub) ACC1(uc) ACC1(ud) ACC1(ue) ACC1(uf)
  }
  for (; j + 4 <= hi; j += 4) {
    int s0 = csr[j+0], s1 = csr[j+1], s2 = csr[j+2], s3 = csr[j+3];
    unsigned u0 = h[(size_t)s0 * 64 + lane];
    unsigned u1 = h[(size_t)s1 * 64 + lane];
    unsigned u2 = h[(size_t)s2 * 64 + lane];
    unsigned u3 = h[(size_t)s3 * 64 + lane];
    ACC1(u0) ACC1(u1) ACC1(u2) ACC1(u3)
  }
  for (; j < hi; ++j) {
    int s = csr[j];
    unsigned u = h[(size_t)s * 64 + lane];
    ACC1(u)
  }
#undef ACC1
  float sc = nd[w];
  float2 bb = ((const float2*)b1)[lane];
  float ox = fmaxf(sx * sc + bb.x, 0.f);
  float oy = fmaxf(sy * sc + bb.y, 0.f);
  ushort2 o; o.x = f2bf(ox); o.y = f2bf(oy);
  ((ushort2*)x2)[(size_t)w * 64 + lane] = o;
}

// ---------------- gather2 (2 nodes/wave, 16-deep) ----------------
__global__ void gather2(const ushort* __restrict__ h2, const int* __restrict__ off,
                        const int* __restrict__ csr, const float* __restrict__ nd,
                        const float* __restrict__ b2, float* __restrict__ out, int N) {
  int wv = (blockIdx.x * blockDim.x + threadIdx.x) >> 6;
  int lane = threadIdx.x & 63;
  int grp = lane >> 5;
  int sub = lane & 31;
  int node = wv * 2 + grp;
  if (node >= N) return;
  int lo = off[node], hi = off[node + 1];
  const unsigned* h = (const unsigned*)h2;
  float s0f = 0.f, s1f = 0.f;
#define ACC2(u) { s0f += __builtin_bit_cast(float, (u) << 16); \
                  s1f += __builtin_bit_cast(float, (u) & 0xFFFF0000u); }
  int j = lo;
  for (; j + 16 <= hi; j += 16) {
    int i0 = csr[j+0], i1 = csr[j+1], i2 = csr[j+2], i3 = csr[j+3];
    int i4 = csr[j+4], i5 = csr[j+5], i6 = csr[j+6], i7 = csr[j+7];
    int i8 = csr[j+8], i9 = csr[j+9], ia = csr[j+10], ib = csr[j+11];
    int ic = csr[j+12], id = csr[j+13], ie = csr[j+14], if_ = csr[j+15];
    unsigned u0 = h[(size_t)i0 * 32 + sub];
    unsigned u1 = h[(size_t)i1 * 32 + sub];
    unsigned u2 = h[(size_t)i2 * 32 + sub];
    unsigned u3 = h[(size_t)i3 * 32 + sub];
    unsigned u4 = h[(size_t)i4 * 32 + sub];
    unsigned u5 = h[(size_t)i5 * 32 + sub];
    unsigned u6 = h[(size_t)i6 * 32 + sub];
    unsigned u7 = h[(size_t)i7 * 32 + sub];
    unsigned u8 = h[(size_t)i8 * 32 + sub];
    unsigned u9 = h[(size_t)i9 * 32 + sub];
    unsigned ua = h[(size_t)ia * 32 + sub];
    unsigned ub = h[(size_t)ib * 32 + sub];
    unsigned uc = h[(size_t)ic * 32 + sub];
    unsigned ud = h[(size_t)id * 32 + sub];
    unsigned ue = h[(size_t)ie * 32 + sub];
    unsigned uf = h[(size_t)if_ * 32 + sub];
    ACC2(u0) ACC2(u1) ACC2(u2) ACC2(u3) ACC2(u4) ACC2(u5) ACC2(u6) ACC2(u7)
    ACC2(u8) ACC2(u9) ACC2(ua) ACC2(ub) ACC2(uc) ACC2(ud) ACC2(ue) ACC2(uf)
  }
  for (; j + 4 <= hi; j += 4) {
    int i0 = csr[j+0], i1 = csr[j+1], i2 = csr[j+2], i3 = csr[j+3];
    unsigned u0 = h[(size_t)i0 * 32 + sub];
    unsigned u1 = h[(size_t)i1 * 32 + sub];
    unsigned u2 = h[(size_t)i2 * 32 + sub];
    unsigned u3 = h[(size_t)i3 * 32 + sub];
    ACC2(u0) ACC2(u1) ACC2(u2) ACC2(u3)
  }
  for (; j < hi; ++j) {
    int i0 = csr[j];
    unsigned u = h[(size_t)i0 * 32 + sub];
    ACC2(u)
  }
#undef ACC2
  float scn = nd[node];
  float2 bb = ((const float2*)b2)[sub];
  float v0 = s0f * scn + bb.x;
  float v1 = s1f * scn + bb.y;
  float2 o;
  o.x = 1.f / (1.f + expf(-v0));
  o.y = 1.f / (1.f + expf(-v1));
  ((float2*)out)[(size_t)node * 32 + sub] = o;
}

extern "C" void kernel_launch(void* const* d_in, const int* in_sizes, int n_in,
                              void* d_out, int out_size, void* d_ws, size_t ws_size,
                              hipStream_t stream) {
  const float* feat = (const float*)d_in[0];
  const int*   src  = (const int*)d_in[1];
  const int*   dst  = (const int*)d_in[2];
  const float* W1   = (const float*)d_in[3];
  const float* b1   = (const float*)d_in[4];
  const float* W2   = (const float*)d_in[5];
  const float* b2   = (const float*)d_in[6];
  float* out = (float*)d_out;

  const int N = in_sizes[0] / IN_F;   // 100000
  const int E = in_sizes[1];          // 1600000

  const int NBK  = (N + 255) >> 8;            // 391 coarse buckets
  const int NBLK = (E + EPB - 1) / EPB;       // 391 sort blocks
  const int HLEN = 2 * NBK * NBLK;

  size_t off = 0;
  auto alloc = [&](size_t bytes) -> void* {
    void* p = (char*)d_ws + off;
    off = (off + bytes + 255) & ~(size_t)255;
    return p;
  };
  int*    hist    = (int*)alloc((size_t)HLEN * 4);
  int*    P       = (int*)alloc((size_t)(HLEN + 1) * 4);
  int*    bsum    = (int*)alloc((size_t)1024 * 4);
  int*    pairs_pk= (int*)alloc((size_t)E * 4);
  int*    srcs_s  = (int*)alloc((size_t)E * 4);
  float*  norm_s  = (float*)alloc((size_t)N * 4);
  float*  norm_d  = (float*)alloc((size_t)N * 4);
  int*    row_off = (int*)alloc((size_t)(N + 1) * 4);
  int*    csr     = (int*)alloc((size_t)E * 4);
  ushort* w1t     = (ushort*)alloc((size_t)H_F * IN_F * 2);
  ushort* w2t     = (ushort*)alloc((size_t)N_CLS * H_F * 2);
  ushort* h1      = (ushort*)alloc((size_t)N * H_F * 2);
  ushort* x2bf    = (ushort*)alloc((size_t)N * H_F * 2);
  ushort* h2      = (ushort*)alloc((size_t)N * N_CLS * 2);
  (void)ws_size;

  conv_w<<<(IN_F * H_F + H_F * N_CLS + 255) / 256, 256, 0, stream>>>(W1, w1t, W2, w2t);

  // graph build (atomic-free)
  hist_kernel<<<NBLK, 256, 0, stream>>>(src, dst, hist, NBK, NBLK, E);
  const int NBS = (HLEN + SCAN_CHUNK - 1) / SCAN_CHUNK;
  scan_part<<<NBS, 256, 0, stream>>>(hist, bsum, HLEN);
  scan_bsum<<<1, 1024, 0, stream>>>(bsum, NBS);
  scan_final<<<NBS, 256, 0, stream>>>(hist, bsum, P, HLEN, 2 * E);
  scatter_kernel<<<NBLK, 256, 0, stream>>>(src, dst, P, pairs_pk, srcs_s, NBK, NBLK, E);
  csr_outdeg_bucket<<<NBK, 256, 0, stream>>>(pairs_pk, srcs_s, P, row_off,
                                             norm_d, norm_s, csr, NBK, NBLK, N, E);

  // layer 1 (conv fused into GEMM A-stage)
  mfma_gemm1<<<(N + 127) / 128, 256, 0, stream>>>(feat, w1t, norm_s, h1, N);
  gather1<<<(N * 64 + 255) / 256, 256, 0, stream>>>(h1, row_off, csr, norm_d, b1, x2bf, N);

  // layer 2
  mfma_gemm_scale<128, 64, 128, 2, 2><<<(N + 127) / 128, 256, 0, stream>>>(
      x2bf, w2t, norm_s, h2, N);
  int pairs = (N + 1) / 2;
  gather2<<<(pairs * 64 + 255) / 256, 256, 0, stream>>>(h2, row_off, csr, norm_d, b2, out, N);
}

// Round 11
// 215.095 us; speedup vs baseline: 1.1445x; 1.0363x over previous
//
#include <hip/hip_runtime.h>
#include <cmath>

#define IN_F 256
#define H_F  128
#define N_CLS 64
#define SCAN_CHUNK 2048   // 256 threads * 8 elems
#define EPB 4096          // edges per block in sort kernels
#define MAXBK 400         // max coarse buckets (ceil(100096/256)=391)

typedef __attribute__((ext_vector_type(8))) short bf16x8;
typedef __attribute__((ext_vector_type(4))) float f32x4;

__device__ __forceinline__ ushort f2bf(float x) {
  unsigned b = __builtin_bit_cast(unsigned, x);
  b += 0x7FFF + ((b >> 16) & 1);          // RNE
  return (ushort)(b >> 16);
}

// ---------------- hist (blocks 0..NBLK-1) + weight conv (blocks NBLK..) ----------------
__global__ __launch_bounds__(256) void hist_conv_kernel(
    const int* __restrict__ src, const int* __restrict__ dst, int* __restrict__ hist,
    const float* __restrict__ W1, ushort* __restrict__ W1T,
    const float* __restrict__ W2, ushort* __restrict__ W2T,
    int NBK, int NBLK, int E) {
  int blk = blockIdx.x, t = threadIdx.x;
  if (blk >= NBLK) {
    int i = (blk - NBLK) * 256 + t;
    if (i < IN_F * H_F) {
      int k = i / H_F, n = i % H_F;
      W1T[n * IN_F + k] = f2bf(W1[i]);
    } else if (i < IN_F * H_F + H_F * N_CLS) {
      int j = i - IN_F * H_F;
      int k = j / N_CLS, n = j % N_CLS;
      W2T[n * H_F + k] = f2bf(W2[j]);
    }
    return;
  }
  __shared__ int hD[MAXBK], hS[MAXBK];
  for (int b = t; b < NBK; b += 256) { hD[b] = 0; hS[b] = 0; }
  __syncthreads();
  int e0 = blk * EPB;
#pragma unroll
  for (int j = 0; j < EPB / 256; ++j) {
    int idx = e0 + j * 256 + t;
    if (idx < E) {
      atomicAdd(&hD[dst[idx] >> 8], 1);
      atomicAdd(&hS[src[idx] >> 8], 1);
    }
  }
  __syncthreads();
  for (int b = t; b < NBK; b += 256) {
    hist[(size_t)b * NBLK + blk] = hD[b];
    hist[(size_t)(NBK + b) * NBLK + blk] = hS[b];
  }
}

// exclusive scan of cnt[0..nbk) into pos[0..nbk), nbk <= 512, 256 threads
__device__ void excl_scan_lds(int* cnt, int* pos, int t, int nbk) {
  for (int b = t; b < nbk; b += 256) pos[b] = cnt[b];
  __syncthreads();
  for (int d = 1; d < 256; d <<= 1) {
    int u = (t < nbk && t >= d) ? pos[t - d] : 0;
    __syncthreads();
    if (t < nbk && t >= d) pos[t] += u;
    __syncthreads();
  }
  int m2 = nbk - 256;
  int s0 = (m2 > 0) ? pos[255] : 0;
  for (int d = 1; d < 256; d <<= 1) {
    int u = (m2 > 0 && t < m2 && t >= d) ? pos[256 + t - d] : 0;
    __syncthreads();
    if (m2 > 0 && t < m2 && t >= d) pos[256 + t] += u;
    __syncthreads();
  }
  if (m2 > 0 && t < m2) pos[256 + t] += s0;
  __syncthreads();
  for (int b = t; b < nbk; b += 256) pos[b] -= cnt[b];
  __syncthreads();
}

// pairs packed: (src<<8)|(dst&255); side array carries coarse bucket for writeout.
__global__ __launch_bounds__(256) void scatter_kernel(const int* __restrict__ src,
                                                      const int* __restrict__ dst,
                                                      const int* __restrict__ P,
                                                      int* __restrict__ pairs_pk,
                                                      int* __restrict__ srcs_s,
                                                      int NBK, int NBLK, int E) {
  __shared__ int cnt[MAXBK], pos[MAXBK], cur[MAXBK], gb[MAXBK];
  __shared__ int stage_pk[EPB];
  __shared__ ushort stage_b[EPB];
  int t = threadIdx.x, blk = blockIdx.x;
  int e0 = blk * EPB;
  int ne = E - e0; if (ne > EPB) ne = EPB;

  // ---- D phase ----
  for (int b = t; b < NBK; b += 256) cnt[b] = 0;
  __syncthreads();
#pragma unroll
  for (int j = 0; j < EPB / 256; ++j) {
    int idx = e0 + j * 256 + t;
    if (idx < E) atomicAdd(&cnt[dst[idx] >> 8], 1);
  }
  __syncthreads();
  excl_scan_lds(cnt, pos, t, NBK);
  for (int b = t; b < NBK; b += 256) { cur[b] = pos[b]; gb[b] = P[(size_t)b * NBLK + blk]; }
  __syncthreads();
#pragma unroll
  for (int j = 0; j < EPB / 256; ++j) {
    int idx = e0 + j * 256 + t;
    if (idx < E) {
      int d = dst[idx];
      int r = atomicAdd(&cur[d >> 8], 1);
      stage_pk[r] = (src[idx] << 8) | (d & 255);
      stage_b[r] = (ushort)(d >> 8);
    }
  }
  __syncthreads();
  for (int i = t; i < ne; i += 256) {
    int b = stage_b[i];
    pairs_pk[gb[b] + (i - pos[b])] = stage_pk[i];
  }
  __syncthreads();

  // ---- S phase ----
  for (int b = t; b < NBK; b += 256) cnt[b] = 0;
  __syncthreads();
#pragma unroll
  for (int j = 0; j < EPB / 256; ++j) {
    int idx = e0 + j * 256 + t;
    if (idx < E) atomicAdd(&cnt[src[idx] >> 8], 1);
  }
  __syncthreads();
  excl_scan_lds(cnt, pos, t, NBK);
  for (int b = t; b < NBK; b += 256) {
    cur[b] = pos[b];
    gb[b] = P[(size_t)(NBK + b) * NBLK + blk] - E;
  }
  __syncthreads();
#pragma unroll
  for (int j = 0; j < EPB / 256; ++j) {
    int idx = e0 + j * 256 + t;
    if (idx < E) {
      int s = src[idx];
      int r = atomicAdd(&cur[s >> 8], 1);
      stage_pk[r] = s;
    }
  }
  __syncthreads();
  for (int i = t; i < ne; i += 256) {
    int s = stage_pk[i];
    int b = s >> 8;
    srcs_s[gb[b] + (i - pos[b])] = s;
  }
}

// per-bucket CSR + in-degree norm + out-degree norm (merged). One block per bucket.
__global__ __launch_bounds__(256) void csr_outdeg_bucket(
    const int* __restrict__ pairs_pk, const int* __restrict__ srcs_s,
    const int* __restrict__ P, int* __restrict__ row_off,
    float* __restrict__ norm_d, float* __restrict__ norm_s,
    int* __restrict__ csr, int NBK, int NBLK, int N, int E) {
  __shared__ int cnt[256], pos[256], cur[256];
  int b = blockIdx.x, t = threadIdx.x;
  int node = b * 256 + t;

  // ---- CSR + norm_d from dst-sorted packed pairs ----
  int bstart = P[(size_t)b * NBLK];
  int bend = (b + 1 < NBK) ? P[(size_t)(b + 1) * NBLK] : E;
  cnt[t] = 0;
  __syncthreads();
  for (int i = bstart + t; i < bend; i += 256) atomicAdd(&cnt[pairs_pk[i] & 255], 1);
  __syncthreads();
  pos[t] = cnt[t];
  __syncthreads();
  for (int d = 1; d < 256; d <<= 1) {
    int u = (t >= d) ? pos[t - d] : 0;
    __syncthreads();
    if (t >= d) pos[t] += u;
    __syncthreads();
  }
  int excl = pos[t] - cnt[t];
  if (node < N) {
    row_off[node] = bstart + excl;
    norm_d[node] = cnt[t] > 0 ? rsqrtf((float)cnt[t]) : 0.f;
  }
  if (b == NBK - 1 && t == 255) row_off[N] = E;
  cur[t] = excl;
  __syncthreads();
  for (int i = bstart + t; i < bend; i += 256) {
    int pk = pairs_pk[i];
    int r = atomicAdd(&cur[pk & 255], 1);
    csr[bstart + r] = (int)((unsigned)pk >> 8);
  }
  __syncthreads();

  // ---- norm_s from src-sorted values ----
  size_t SOFF = (size_t)NBK * NBLK;
  int sstart = P[SOFF + (size_t)b * NBLK] - E;
  int send = (b + 1 < NBK) ? P[SOFF + (size_t)(b + 1) * NBLK] - E : E;
  cnt[t] = 0;
  __syncthreads();
  for (int i = sstart + t; i < send; i += 256) atomicAdd(&cnt[srcs_s[i] & 255], 1);
  __syncthreads();
  if (node < N) norm_s[node] = cnt[t] > 0 ? rsqrtf((float)cnt[t]) : 0.f;
}

// ---------------- generic 3-kernel decoupled scan ----------------
__global__ void scan_part(const int* __restrict__ arr, int* __restrict__ bsum, int len) {
  int base = blockIdx.x * SCAN_CHUNK + threadIdx.x * 8;
  int s = 0;
#pragma unroll
  for (int j = 0; j < 8; ++j) {
    int i = base + j;
    if (i < len) s += arr[i];
  }
#pragma unroll
  for (int d = 1; d < 64; d <<= 1) s += __shfl_xor(s, d);
  __shared__ int ws[4];
  int lane = threadIdx.x & 63, w = threadIdx.x >> 6;
  if (lane == 0) ws[w] = s;
  __syncthreads();
  if (threadIdx.x == 0) bsum[blockIdx.x] = ws[0] + ws[1] + ws[2] + ws[3];
}

__global__ __launch_bounds__(1024) void scan_bsum(int* __restrict__ bsum, int nb) {
  __shared__ int sm[1024];
  int t = threadIdx.x;
  sm[t] = (t < nb) ? bsum[t] : 0;
  __syncthreads();
  for (int d = 1; d < 1024; d <<= 1) {
    int v = (t >= d) ? sm[t - d] : 0;
    __syncthreads();
    sm[t] += v;
    __syncthreads();
  }
  if (t < nb) bsum[t] = (t == 0) ? 0 : sm[t - 1];   // exclusive
}

__global__ void scan_final(const int* __restrict__ arr, const int* __restrict__ bsum_ex,
                           int* __restrict__ outp, int len, int total) {
  int base = blockIdx.x * SCAN_CHUNK + threadIdx.x * 8;
  int v[8], pre[8];
  int s = 0;
#pragma unroll
  for (int j = 0; j < 8; ++j) {
    int i = base + j;
    v[j] = (i < len) ? arr[i] : 0;
    pre[j] = s;
    s += v[j];
  }
  int lane = threadIdx.x & 63, w = threadIdx.x >> 6;
  int inc = s;
#pragma unroll
  for (int d = 1; d < 64; d <<= 1) {
    int u = __shfl_up(inc, d);
    if (lane >= d) inc += u;
  }
  __shared__ int wsum[4], woff[4];
  if (lane == 63) wsum[w] = inc;
  __syncthreads();
  if (threadIdx.x == 0) {
    int r = 0;
    for (int q = 0; q < 4; ++q) { woff[q] = r; r += wsum[q]; }
  }
  __syncthreads();
  int ex = (inc - s) + woff[w] + bsum_ex[blockIdx.x];
#pragma unroll
  for (int j = 0; j < 8; ++j) {
    int i = base + j;
    if (i < len) outp[i] = ex + pre[j];
  }
  if (blockIdx.x == 0 && threadIdx.x == 0) outp[len] = total;
}

// ---------------- layer-1 GEMM: f32 A, async reg-staged convert, bf16 MFMA ----
// T14 async-split: A-tile k+1 global loads issued during tile k's staging; their
// waitcnt lands at the barrier, overlapping B's global_load_lds drain.
__global__ __launch_bounds__(256) void mfma_gemm1(
    const float* __restrict__ A, const ushort* __restrict__ BT,
    const float* __restrict__ scale, ushort* __restrict__ C, int M) {
  constexpr int BM = 128, BN = 128, KTOT = 256, BK = 64, WM = 2, WN = 2;
  constexpr int FM = (BM / WM) / 16;   // 4
  constexpr int FN = (BN / WN) / 16;   // 4
  constexpr int ABYTES = BM * BK * 2;  // 16 KB
  constexpr int BBYTES = BN * BK * 2;  // 16 KB
  __shared__ char lds[ABYTES + BBYTES];
  char* Asm = lds;
  char* Bsm = lds + ABYTES;

  const int tid = threadIdx.x;
  const int lane = tid & 63;
  const int w = tid >> 6;
  const int wm = w / WN, wn = w % WN;
  const int m0 = blockIdx.x * BM;

  f32x4 acc[FM][FN];
#pragma unroll
  for (int m = 0; m < FM; ++m)
#pragma unroll
    for (int n = 0; n < FN; ++n) acc[m][n] = (f32x4){0.f, 0.f, 0.f, 0.f};

  const int ra = lane & 15;
  const int kg = lane >> 4;

  float4 pfa[8];
  // prologue: A-tile 0 into regs
#pragma unroll
  for (int s = 0; s < 4; ++s) {
    int L = s * 4096 + tid * 16;
    int r = L >> 7;
    int slot = (L >> 4) & 7;
    int gr = m0 + r; if (gr >= M) gr = M - 1;
    const float4* gp = (const float4*)(A + (size_t)gr * KTOT + slot * 8);
    pfa[2 * s] = gp[0];
    pfa[2 * s + 1] = gp[1];
  }

  for (int kt = 0; kt < KTOT / BK; ++kt) {
    // write staged A regs -> bf16 -> swizzled LDS
#pragma unroll
    for (int s = 0; s < 4; ++s) {
      int L = s * 4096 + tid * 16;
      int r = L >> 7;
      float4 va = pfa[2 * s], vb = pfa[2 * s + 1];
      bf16x8 o;
      o[0] = (short)f2bf(va.x); o[1] = (short)f2bf(va.y);
      o[2] = (short)f2bf(va.z); o[3] = (short)f2bf(va.w);
      o[4] = (short)f2bf(vb.x); o[5] = (short)f2bf(vb.y);
      o[6] = (short)f2bf(vb.z); o[7] = (short)f2bf(vb.w);
      *(bf16x8*)(Asm + (L ^ ((r & 7) << 4))) = o;
    }
    // B tile via global_load_lds (pre-swizzled source)
#pragma unroll
    for (int s = 0; s < BBYTES / 4096; ++s) {
      int L = s * 4096 + tid * 16;
      int r = L >> 7;
      int slot = (L >> 4) & 7;
      const char* gp = (const char*)BT + (size_t)r * (KTOT * 2) + kt * (BK * 2)
                     + ((slot * 16) ^ ((r & 7) << 4));
      __builtin_amdgcn_global_load_lds(
          (const __attribute__((address_space(1))) unsigned*)gp,
          (__attribute__((address_space(3))) unsigned*)(Bsm + L), 16, 0, 0);
    }
    // issue next A-tile loads (consumed after next barrier)
    if (kt + 1 < KTOT / BK) {
#pragma unroll
      for (int s = 0; s < 4; ++s) {
        int L = s * 4096 + tid * 16;
        int r = L >> 7;
        int slot = (L >> 4) & 7;
        int gr = m0 + r; if (gr >= M) gr = M - 1;
        const float4* gp = (const float4*)(A + (size_t)gr * KTOT + (kt + 1) * BK + slot * 8);
        pfa[2 * s] = gp[0];
        pfa[2 * s + 1] = gp[1];
      }
    }
    __syncthreads();

#pragma unroll
    for (int ks = 0; ks < 2; ++ks) {
      bf16x8 af[FM], bfr[FN];
#pragma unroll
      for (int m = 0; m < FM; ++m) {
        int r = wm * (BM / WM) + m * 16 + ra;
        int cb = ks * 64 + kg * 16;
        af[m] = *(const bf16x8*)(Asm + r * 128 + (cb ^ ((r & 7) << 4)));
      }
#pragma unroll
      for (int n = 0; n < FN; ++n) {
        int c = wn * (BN / WN) + n * 16 + ra;
        int cb = ks * 64 + kg * 16;
        bfr[n] = *(const bf16x8*)(Bsm + c * 128 + (cb ^ ((c & 7) << 4)));
      }
#pragma unroll
      for (int m = 0; m < FM; ++m)
#pragma unroll
        for (int n = 0; n < FN; ++n)
          acc[m][n] = __builtin_amdgcn_mfma_f32_16x16x32_bf16(af[m], bfr[n], acc[m][n], 0, 0, 0);
    }
    __syncthreads();
  }

#pragma unroll
  for (int m = 0; m < FM; ++m) {
#pragma unroll
    for (int j = 0; j < 4; ++j) {
      int rl = wm * (BM / WM) + m * 16 + (lane >> 4) * 4 + j;
      int gr = m0 + rl;
      if (gr < M) {
        float sc = scale[gr];
#pragma unroll
        for (int n = 0; n < FN; ++n) {
          int c = wn * (BN / WN) + n * 16 + (lane & 15);
          C[(size_t)gr * BN + c] = f2bf(acc[m][n][j] * sc);
        }
      }
    }
  }
}

// ---------------- layer-2 GEMM (bf16 A via global_load_lds) ----------------
template<int BM, int BN, int KTOT, int WM, int WN>
__global__ __launch_bounds__(256) void mfma_gemm_scale(
    const ushort* __restrict__ A, const ushort* __restrict__ BT,
    const float* __restrict__ scale, ushort* __restrict__ C, int M) {
  constexpr int BK = 64;
  constexpr int FM = (BM / WM) / 16;
  constexpr int FN = (BN / WN) / 16;
  constexpr int ABYTES = BM * BK * 2;
  constexpr int BBYTES = BN * BK * 2;
  __shared__ char lds[ABYTES + BBYTES];
  char* Asm = lds;
  char* Bsm = lds + ABYTES;

  const int tid = threadIdx.x;
  const int lane = tid & 63;
  const int w = tid >> 6;
  const int wm = w / WN, wn = w % WN;
  const int m0 = blockIdx.x * BM;

  f32x4 acc[FM][FN];
#pragma unroll
  for (int m = 0; m < FM; ++m)
#pragma unroll
    for (int n = 0; n < FN; ++n) acc[m][n] = (f32x4){0.f, 0.f, 0.f, 0.f};

  const int ra = lane & 15;
  const int kg = lane >> 4;

  for (int kt = 0; kt < KTOT / BK; ++kt) {
#pragma unroll
    for (int s = 0; s < ABYTES / 4096; ++s) {
      int L = s * 4096 + tid * 16;
      int r = L >> 7;
      int slot = (L >> 4) & 7;
      int gr = m0 + r; if (gr >= M) gr = M - 1;
      const char* gp = (const char*)A + (size_t)gr * (KTOT * 2) + kt * (BK * 2)
                     + ((slot * 16) ^ ((r & 7) << 4));
      __builtin_amdgcn_global_load_lds(
          (const __attribute__((address_space(1))) unsigned*)gp,
          (__attribute__((address_space(3))) unsigned*)(Asm + L), 16, 0, 0);
    }
#pragma unroll
    for (int s = 0; s < BBYTES / 4096; ++s) {
      int L = s * 4096 + tid * 16;
      int r = L >> 7;
      int slot = (L >> 4) & 7;
      const char* gp = (const char*)BT + (size_t)r * (KTOT * 2) + kt * (BK * 2)
                     + ((slot * 16) ^ ((r & 7) << 4));
      __builtin_amdgcn_global_load_lds(
          (const __attribute__((address_space(1))) unsigned*)gp,
          (__attribute__((address_space(3))) unsigned*)(Bsm + L), 16, 0, 0);
    }
    __syncthreads();

#pragma unroll
    for (int ks = 0; ks < 2; ++ks) {
      bf16x8 af[FM], bfr[FN];
#pragma unroll
      for (int m = 0; m < FM; ++m) {
        int r = wm * (BM / WM) + m * 16 + ra;
        int cb = ks * 64 + kg * 16;
        af[m] = *(const bf16x8*)(Asm + r * 128 + (cb ^ ((r & 7) << 4)));
      }
#pragma unroll
      for (int n = 0; n < FN; ++n) {
        int c = wn * (BN / WN) + n * 16 + ra;
        int cb = ks * 64 + kg * 16;
        bfr[n] = *(const bf16x8*)(Bsm + c * 128 + (cb ^ ((c & 7) << 4)));
      }
#pragma unroll
      for (int m = 0; m < FM; ++m)
#pragma unroll
        for (int n = 0; n < FN; ++n)
          acc[m][n] = __builtin_amdgcn_mfma_f32_16x16x32_bf16(af[m], bfr[n], acc[m][n], 0, 0, 0);
    }
    __syncthreads();
  }

#pragma unroll
  for (int m = 0; m < FM; ++m) {
#pragma unroll
    for (int j = 0; j < 4; ++j) {
      int rl = wm * (BM / WM) + m * 16 + (lane >> 4) * 4 + j;
      int gr = m0 + rl;
      if (gr < M) {
        float sc = scale[gr];
#pragma unroll
        for (int n = 0; n < FN; ++n) {
          int c = wn * (BN / WN) + n * 16 + (lane & 15);
          C[(size_t)gr * BN + c] = f2bf(acc[m][n][j] * sc);
        }
      }
    }
  }
}

// ---------------- gather1 (1 node/wave, 16-deep MLP unroll) ----------------
__global__ void gather1(const ushort* __restrict__ h1, const int* __restrict__ off,
                        const int* __restrict__ csr, const float* __restrict__ nd,
                        const float* __restrict__ b1, ushort* __restrict__ x2, int N) {
  int w = (blockIdx.x * blockDim.x + threadIdx.x) >> 6;
  int lane = threadIdx.x & 63;
  if (w >= N) return;
  int lo = off[w], hi = off[w + 1];
  const unsigned* h = (const unsigned*)h1;
  float sx = 0.f, sy = 0.f;
#define ACC1(u) { sx += __builtin_bit_cast(float, (u) << 16); \
                  sy += __builtin_bit_cast(float, (u) & 0xFFFF0000u); }
  int j = lo;
  for (; j + 16 <= hi; j += 16) {
    int s0 = csr[j+0], s1 = csr[j+1], s2 = csr[j+2], s3 = csr[j+3];
    int s4 = csr[j+4], s5 = csr[j+5], s6 = csr[j+6], s7 = csr[j+7];
    int s8 = csr[j+8], s9 = csr[j+9], sa = csr[j+10], sb = csr[j+11];
    int sc_ = csr[j+12], sd = csr[j+13], se = csr[j+14], sf = csr[j+15];
    unsigned u0 = h[(size_t)s0 * 64 + lane];
    unsigned u1 = h[(size_t)s1 * 64 + lane];
    unsigned u2 = h[(size_t)s2 * 64 + lane];
    unsigned u3 = h[(size_t)s3 * 64 + lane];
    unsigned u4 = h[(size_t)s4 * 64 + lane];
    unsigned u5 = h[(size_t)s5 * 64 + lane];
    unsigned u6 = h[(size_t)s6 * 64 + lane];
    unsigned u7 = h[(size_t)s7 * 64 + lane];
    unsigned u8 = h[(size_t)s8 * 64 + lane];
    unsigned u9 = h[(size_t)s9 * 64 + lane];
    unsigned ua = h[(size_t)sa * 64 + lane];
    unsigned ub = h[(size_t)sb * 64 + lane];
    unsigned uc = h[(size_t)sc_ * 64 + lane];
    unsigned ud = h[(size_t)sd * 64 + lane];
    unsigned ue = h[(size_t)se * 64 + lane];
    unsigned uf = h[(size_t)sf * 64 + lane];
    ACC1(u0) ACC1(u1) ACC1(u2) ACC1(u3) ACC1(u4) ACC1(u5) ACC1(u6) ACC1(u7)
    ACC1(u8) ACC1(u9) ACC1(ua) ACC1(ub) ACC1(uc) ACC1(ud) ACC1(ue) ACC1(uf)
  }
  for (; j + 4 <= hi; j += 4) {
    int s0 = csr[j+0], s1 = csr[j+1], s2 = csr[j+2], s3 = csr[j+3];
    unsigned u0 = h[(size_t)s0 * 64 + lane];
    unsigned u1 = h[(size_t)s1 * 64 + lane];
    unsigned u2 = h[(size_t)s2 * 64 + lane];
    unsigned u3 = h[(size_t)s3 * 64 + lane];
    ACC1(u0) ACC1(u1) ACC1(u2) ACC1(u3)
  }
  for (; j < hi; ++j) {
    int s = csr[j];
    unsigned u = h[(size_t)s * 64 + lane];
    ACC1(u)
  }
#undef ACC1
  float sc = nd[w];
  float2 bb = ((const float2*)b1)[lane];
  float ox = fmaxf(sx * sc + bb.x, 0.f);
  float oy = fmaxf(sy * sc + bb.y, 0.f);
  ushort2 o; o.x = f2bf(ox); o.y = f2bf(oy);
  ((ushort2*)x2)[(size_t)w * 64 + lane] = o;
}

// ---------------- gather2 (2 nodes/wave, 16-deep) ----------------
__global__ void gather2(const ushort* __restrict__ h2, const int* __restrict__ off,
                        const int* __restrict__ csr, const float* __restrict__ nd,
                        const float* __restrict__ b2, float* __restrict__ out, int N) {
  int wv = (blockIdx.x * blockDim.x + threadIdx.x) >> 6;
  int lane = threadIdx.x & 63;
  int grp = lane >> 5;
  int sub = lane & 31;
  int node = wv * 2 + grp;
  if (node >= N) return;
  int lo = off[node], hi = off[node + 1];
  const unsigned* h = (const unsigned*)h2;
  float s0f = 0.f, s1f = 0.f;
#define ACC2(u) { s0f += __builtin_bit_cast(float, (u) << 16); \
                  s1f += __builtin_bit_cast(float, (u) & 0xFFFF0000u); }
  int j = lo;
  for (; j + 16 <= hi; j += 16) {
    int i0 = csr[j+0], i1 = csr[j+1], i2 = csr[j+2], i3 = csr[j+3];
    int i4 = csr[j+4], i5 = csr[j+5], i6 = csr[j+6], i7 = csr[j+7];
    int i8 = csr[j+8], i9 = csr[j+9], ia = csr[j+10], ib = csr[j+11];
    int ic = csr[j+12], id = csr[j+13], ie = csr[j+14], if_ = csr[j+15];
    unsigned u0 = h[(size_t)i0 * 32 + sub];
    unsigned u1 = h[(size_t)i1 * 32 + sub];
    unsigned u2 = h[(size_t)i2 * 32 + sub];
    unsigned u3 = h[(size_t)i3 * 32 + sub];
    unsigned u4 = h[(size_t)i4 * 32 + sub];
    unsigned u5 = h[(size_t)i5 * 32 + sub];
    unsigned u6 = h[(size_t)i6 * 32 + sub];
    unsigned u7 = h[(size_t)i7 * 32 + sub];
    unsigned u8 = h[(size_t)i8 * 32 + sub];
    unsigned u9 = h[(size_t)i9 * 32 + sub];
    unsigned ua = h[(size_t)ia * 32 + sub];
    unsigned ub = h[(size_t)ib * 32 + sub];
    unsigned uc = h[(size_t)ic * 32 + sub];
    unsigned ud = h[(size_t)id * 32 + sub];
    unsigned ue = h[(size_t)ie * 32 + sub];
    unsigned uf = h[(size_t)if_ * 32 + sub];
    ACC2(u0) ACC2(u1) ACC2(u2) ACC2(u3) ACC2(u4) ACC2(u5) ACC2(u6) ACC2(u7)
    ACC2(u8) ACC2(u9) ACC2(ua) ACC2(ub) ACC2(uc) ACC2(ud) ACC2(ue) ACC2(uf)
  }
  for (; j + 4 <= hi; j += 4) {
    int i0 = csr[j+0], i1 = csr[j+1], i2 = csr[j+2], i3 = csr[j+3];
    unsigned u0 = h[(size_t)i0 * 32 + sub];
    unsigned u1 = h[(size_t)i1 * 32 + sub];
    unsigned u2 = h[(size_t)i2 * 32 + sub];
    unsigned u3 = h[(size_t)i3 * 32 + sub];
    ACC2(u0) ACC2(u1) ACC2(u2) ACC2(u3)
  }
  for (; j < hi; ++j) {
    int i0 = csr[j];
    unsigned u = h[(size_t)i0 * 32 + sub];
    ACC2(u)
  }
#undef ACC2
  float scn = nd[node];
  float2 bb = ((const float2*)b2)[sub];
  float v0 = s0f * scn + bb.x;
  float v1 = s1f * scn + bb.y;
  float2 o;
  o.x = 1.f / (1.f + expf(-v0));
  o.y = 1.f / (1.f + expf(-v1));
  ((float2*)out)[(size_t)node * 32 + sub] = o;
}

extern "C" void kernel_launch(void* const* d_in, const int* in_sizes, int n_in,
                              void* d_out, int out_size, void* d_ws, size_t ws_size,
                              hipStream_t stream) {
  const float* feat = (const float*)d_in[0];
  const int*   src  = (const int*)d_in[1];
  const int*   dst  = (const int*)d_in[2];
  const float* W1   = (const float*)d_in[3];
  const float* b1   = (const float*)d_in[4];
  const float* W2   = (const float*)d_in[5];
  const float* b2   = (const float*)d_in[6];
  float* out = (float*)d_out;

  const int N = in_sizes[0] / IN_F;   // 100000
  const int E = in_sizes[1];          // 1600000

  const int NBK  = (N + 255) >> 8;            // 391 coarse buckets
  const int NBLK = (E + EPB - 1) / EPB;       // 391 sort blocks
  const int HLEN = 2 * NBK * NBLK;
  const int WBLK = (IN_F * H_F + H_F * N_CLS + 255) / 256;   // weight-conv blocks

  size_t off = 0;
  auto alloc = [&](size_t bytes) -> void* {
    void* p = (char*)d_ws + off;
    off = (off + bytes + 255) & ~(size_t)255;
    return p;
  };
  int*    hist    = (int*)alloc((size_t)HLEN * 4);
  int*    P       = (int*)alloc((size_t)(HLEN + 1) * 4);
  int*    bsum    = (int*)alloc((size_t)1024 * 4);
  int*    pairs_pk= (int*)alloc((size_t)E * 4);
  int*    srcs_s  = (int*)alloc((size_t)E * 4);
  float*  norm_s  = (float*)alloc((size_t)N * 4);
  float*  norm_d  = (float*)alloc((size_t)N * 4);
  int*    row_off = (int*)alloc((size_t)(N + 1) * 4);
  int*    csr     = (int*)alloc((size_t)E * 4);
  ushort* w1t     = (ushort*)alloc((size_t)H_F * IN_F * 2);
  ushort* w2t     = (ushort*)alloc((size_t)N_CLS * H_F * 2);
  ushort* h1      = (ushort*)alloc((size_t)N * H_F * 2);
  ushort* x2bf    = (ushort*)alloc((size_t)N * H_F * 2);
  ushort* h2      = (ushort*)alloc((size_t)N * N_CLS * 2);
  (void)ws_size;

  // graph build (atomic-free) + weight conv fused into hist launch
  hist_conv_kernel<<<NBLK + WBLK, 256, 0, stream>>>(src, dst, hist, W1, w1t, W2, w2t,
                                                    NBK, NBLK, E);
  const int NBS = (HLEN + SCAN_CHUNK - 1) / SCAN_CHUNK;
  scan_part<<<NBS, 256, 0, stream>>>(hist, bsum, HLEN);
  scan_bsum<<<1, 1024, 0, stream>>>(bsum, NBS);
  scan_final<<<NBS, 256, 0, stream>>>(hist, bsum, P, HLEN, 2 * E);
  scatter_kernel<<<NBLK, 256, 0, stream>>>(src, dst, P, pairs_pk, srcs_s, NBK, NBLK, E);
  csr_outdeg_bucket<<<NBK, 256, 0, stream>>>(pairs_pk, srcs_s, P, row_off,
                                             norm_d, norm_s, csr, NBK, NBLK, N, E);

  // layer 1 (conv fused into GEMM A-stage, async staging)
  mfma_gemm1<<<(N + 127) / 128, 256, 0, stream>>>(feat, w1t, norm_s, h1, N);
  gather1<<<(N * 64 + 255) / 256, 256, 0, stream>>>(h1, row_off, csr, norm_d, b1, x2bf, N);

  // layer 2
  mfma_gemm_scale<128, 64, 128, 2, 2><<<(N + 127) / 128, 256, 0, stream>>>(
      x2bf, w2t, norm_s, h2, N);
  int pairs = (N + 1) / 2;
  gather2<<<(pairs * 64 + 255) / 256, 256, 0, stream>>>(h2, row_off, csr, norm_d, b2, out, N);
}

// Round 12
// 214.811 us; speedup vs baseline: 1.1460x; 1.0013x over previous
//
#include <hip/hip_runtime.h>
#include <cmath>

#define IN_F 256
#define H_F  128
#define N_CLS 64
#define SCAN_CHUNK 2048   // 256 threads * 8 elems
#define EPB 2048          // edges per block in sort kernels (8 blocks/CU resident)
#define MAXBK 400         // max coarse buckets (ceil(100096/256)=391)

typedef __attribute__((ext_vector_type(8))) short bf16x8;
typedef __attribute__((ext_vector_type(4))) float f32x4;

__device__ __forceinline__ ushort f2bf(float x) {
  unsigned b = __builtin_bit_cast(unsigned, x);
  b += 0x7FFF + ((b >> 16) & 1);          // RNE
  return (ushort)(b >> 16);
}

// ---------------- hist (blocks 0..NBLK-1) + weight conv (blocks NBLK..) ----------------
__global__ __launch_bounds__(256) void hist_conv_kernel(
    const int* __restrict__ src, const int* __restrict__ dst, int* __restrict__ hist,
    const float* __restrict__ W1, ushort* __restrict__ W1T,
    const float* __restrict__ W2, ushort* __restrict__ W2T,
    int NBK, int NBLK, int E) {
  int blk = blockIdx.x, t = threadIdx.x;
  if (blk >= NBLK) {
    int i = (blk - NBLK) * 256 + t;
    if (i < IN_F * H_F) {
      int k = i / H_F, n = i % H_F;
      W1T[n * IN_F + k] = f2bf(W1[i]);
    } else if (i < IN_F * H_F + H_F * N_CLS) {
      int j = i - IN_F * H_F;
      int k = j / N_CLS, n = j % N_CLS;
      W2T[n * H_F + k] = f2bf(W2[j]);
    }
    return;
  }
  __shared__ int hD[MAXBK], hS[MAXBK];
  for (int b = t; b < NBK; b += 256) { hD[b] = 0; hS[b] = 0; }
  __syncthreads();
  int e0 = blk * EPB;
#pragma unroll
  for (int j = 0; j < EPB / 256; ++j) {
    int idx = e0 + j * 256 + t;
    if (idx < E) {
      atomicAdd(&hD[dst[idx] >> 8], 1);
      atomicAdd(&hS[src[idx] >> 8], 1);
    }
  }
  __syncthreads();
  for (int b = t; b < NBK; b += 256) {
    hist[(size_t)b * NBLK + blk] = hD[b];
    hist[(size_t)(NBK + b) * NBLK + blk] = hS[b];
  }
}

// wave-shfl exclusive scan of cnt[0..nbk) into pos[0..nbk), nbk <= 512.
// 2 elements/thread, 6 shfl steps, 2 barriers (vs ~36 for Hillis-Steele LDS).
__device__ void excl_scan_wave(const int* cnt, int* pos, int t, int nbk) {
  __shared__ int wtot[4];
  int lane = t & 63, w = t >> 6;
  int e0 = 2 * t, e1 = 2 * t + 1;
  int a = (e0 < nbk) ? cnt[e0] : 0;
  int b = (e1 < nbk) ? cnt[e1] : 0;
  int s = a + b;
  int inc = s;
#pragma unroll
  for (int d = 1; d < 64; d <<= 1) {
    int u = __shfl_up(inc, d);
    if (lane >= d) inc += u;
  }
  if (lane == 63) wtot[w] = inc;
  __syncthreads();
  int woff = 0;
#pragma unroll
  for (int q = 0; q < 4; ++q) woff += (q < w) ? wtot[q] : 0;
  int ex = woff + inc - s;
  if (e0 < nbk) pos[e0] = ex;
  if (e1 < nbk) pos[e1] = ex + a;
  __syncthreads();
}

// pairs packed: (src<<8)|(dst&255); side array carries coarse bucket for writeout.
__global__ __launch_bounds__(256) void scatter_kernel(const int* __restrict__ src,
                                                      const int* __restrict__ dst,
                                                      const int* __restrict__ P,
                                                      int* __restrict__ pairs_pk,
                                                      int* __restrict__ srcs_s,
                                                      int NBK, int NBLK, int E) {
  __shared__ int cnt[MAXBK], pos[MAXBK], cur[MAXBK], gb[MAXBK];
  __shared__ int stage_pk[EPB];
  __shared__ ushort stage_b[EPB];
  int t = threadIdx.x, blk = blockIdx.x;
  int e0 = blk * EPB;
  int ne = E - e0; if (ne > EPB) ne = EPB;

  // ---- D phase ----
  for (int b = t; b < NBK; b += 256) cnt[b] = 0;
  __syncthreads();
#pragma unroll
  for (int j = 0; j < EPB / 256; ++j) {
    int idx = e0 + j * 256 + t;
    if (idx < E) atomicAdd(&cnt[dst[idx] >> 8], 1);
  }
  __syncthreads();
  excl_scan_wave(cnt, pos, t, NBK);
  for (int b = t; b < NBK; b += 256) { cur[b] = pos[b]; gb[b] = P[(size_t)b * NBLK + blk]; }
  __syncthreads();
#pragma unroll
  for (int j = 0; j < EPB / 256; ++j) {
    int idx = e0 + j * 256 + t;
    if (idx < E) {
      int d = dst[idx];
      int r = atomicAdd(&cur[d >> 8], 1);
      stage_pk[r] = (src[idx] << 8) | (d & 255);
      stage_b[r] = (ushort)(d >> 8);
    }
  }
  __syncthreads();
  for (int i = t; i < ne; i += 256) {
    int b = stage_b[i];
    pairs_pk[gb[b] + (i - pos[b])] = stage_pk[i];
  }
  __syncthreads();

  // ---- S phase ----
  for (int b = t; b < NBK; b += 256) cnt[b] = 0;
  __syncthreads();
#pragma unroll
  for (int j = 0; j < EPB / 256; ++j) {
    int idx = e0 + j * 256 + t;
    if (idx < E) atomicAdd(&cnt[src[idx] >> 8], 1);
  }
  __syncthreads();
  excl_scan_wave(cnt, pos, t, NBK);
  for (int b = t; b < NBK; b += 256) {
    cur[b] = pos[b];
    gb[b] = P[(size_t)(NBK + b) * NBLK + blk] - E;
  }
  __syncthreads();
#pragma unroll
  for (int j = 0; j < EPB / 256; ++j) {
    int idx = e0 + j * 256 + t;
    if (idx < E) {
      int s = src[idx];
      int r = atomicAdd(&cur[s >> 8], 1);
      stage_pk[r] = s;
    }
  }
  __syncthreads();
  for (int i = t; i < ne; i += 256) {
    int s = stage_pk[i];
    int b = s >> 8;
    srcs_s[gb[b] + (i - pos[b])] = s;
  }
}

// per-bucket CSR + in-degree norm + out-degree norm (merged). One block per bucket.
__global__ __launch_bounds__(256) void csr_outdeg_bucket(
    const int* __restrict__ pairs_pk, const int* __restrict__ srcs_s,
    const int* __restrict__ P, int* __restrict__ row_off,
    float* __restrict__ norm_d, float* __restrict__ norm_s,
    int* __restrict__ csr, int NBK, int NBLK, int N, int E) {
  __shared__ int cnt[256], cur[256], wtot[4];
  int b = blockIdx.x, t = threadIdx.x;
  int node = b * 256 + t;
  int lane = t & 63, w = t >> 6;

  // ---- CSR + norm_d from dst-sorted packed pairs ----
  int bstart = P[(size_t)b * NBLK];
  int bend = (b + 1 < NBK) ? P[(size_t)(b + 1) * NBLK] : E;
  cnt[t] = 0;
  __syncthreads();
  for (int i = bstart + t; i < bend; i += 256) atomicAdd(&cnt[pairs_pk[i] & 255], 1);
  __syncthreads();
  // wave-shfl exclusive scan of cnt[256]
  int c = cnt[t];
  int inc = c;
#pragma unroll
  for (int d = 1; d < 64; d <<= 1) {
    int u = __shfl_up(inc, d);
    if (lane >= d) inc += u;
  }
  if (lane == 63) wtot[w] = inc;
  __syncthreads();
  int woff = 0;
#pragma unroll
  for (int q = 0; q < 4; ++q) woff += (q < w) ? wtot[q] : 0;
  int excl = woff + inc - c;
  if (node < N) {
    row_off[node] = bstart + excl;
    norm_d[node] = c > 0 ? rsqrtf((float)c) : 0.f;
  }
  if (b == NBK - 1 && t == 255) row_off[N] = E;
  cur[t] = excl;
  __syncthreads();
  for (int i = bstart + t; i < bend; i += 256) {
    int pk = pairs_pk[i];
    int r = atomicAdd(&cur[pk & 255], 1);
    csr[bstart + r] = (int)((unsigned)pk >> 8);
  }
  __syncthreads();

  // ---- norm_s from src-sorted values ----
  size_t SOFF = (size_t)NBK * NBLK;
  int sstart = P[SOFF + (size_t)b * NBLK] - E;
  int send = (b + 1 < NBK) ? P[SOFF + (size_t)(b + 1) * NBLK] - E : E;
  cnt[t] = 0;
  __syncthreads();
  for (int i = sstart + t; i < send; i += 256) atomicAdd(&cnt[srcs_s[i] & 255], 1);
  __syncthreads();
  if (node < N) norm_s[node] = cnt[t] > 0 ? rsqrtf((float)cnt[t]) : 0.f;
}

// ---------------- generic 3-kernel decoupled scan ----------------
__global__ void scan_part(const int* __restrict__ arr, int* __restrict__ bsum, int len) {
  int base = blockIdx.x * SCAN_CHUNK + threadIdx.x * 8;
  int s = 0;
#pragma unroll
  for (int j = 0; j < 8; ++j) {
    int i = base + j;
    if (i < len) s += arr[i];
  }
#pragma unroll
  for (int d = 1; d < 64; d <<= 1) s += __shfl_xor(s, d);
  __shared__ int ws[4];
  int lane = threadIdx.x & 63, w = threadIdx.x >> 6;
  if (lane == 0) ws[w] = s;
  __syncthreads();
  if (threadIdx.x == 0) bsum[blockIdx.x] = ws[0] + ws[1] + ws[2] + ws[3];
}

__global__ __launch_bounds__(1024) void scan_bsum(int* __restrict__ bsum, int nb) {
  __shared__ int sm[1024];
  int t = threadIdx.x;
  sm[t] = (t < nb) ? bsum[t] : 0;
  __syncthreads();
  for (int d = 1; d < 1024; d <<= 1) {
    int v = (t >= d) ? sm[t - d] : 0;
    __syncthreads();
    sm[t] += v;
    __syncthreads();
  }
  if (t < nb) bsum[t] = (t == 0) ? 0 : sm[t - 1];   // exclusive
}

__global__ void scan_final(const int* __restrict__ arr, const int* __restrict__ bsum_ex,
                           int* __restrict__ outp, int len, int total) {
  int base = blockIdx.x * SCAN_CHUNK + threadIdx.x * 8;
  int v[8], pre[8];
  int s = 0;
#pragma unroll
  for (int j = 0; j < 8; ++j) {
    int i = base + j;
    v[j] = (i < len) ? arr[i] : 0;
    pre[j] = s;
    s += v[j];
  }
  int lane = threadIdx.x & 63, w = threadIdx.x >> 6;
  int inc = s;
#pragma unroll
  for (int d = 1; d < 64; d <<= 1) {
    int u = __shfl_up(inc, d);
    if (lane >= d) inc += u;
  }
  __shared__ int wsum[4], woff[4];
  if (lane == 63) wsum[w] = inc;
  __syncthreads();
  if (threadIdx.x == 0) {
    int r = 0;
    for (int q = 0; q < 4; ++q) { woff[q] = r; r += wsum[q]; }
  }
  __syncthreads();
  int ex = (inc - s) + woff[w] + bsum_ex[blockIdx.x];
#pragma unroll
  for (int j = 0; j < 8; ++j) {
    int i = base + j;
    if (i < len) outp[i] = ex + pre[j];
  }
  if (blockIdx.x == 0 && threadIdx.x == 0) outp[len] = total;
}

// ---------------- layer-1 GEMM: f32 A, async reg-staged convert, bf16 MFMA ----
__global__ __launch_bounds__(256) void mfma_gemm1(
    const float* __restrict__ A, const ushort* __restrict__ BT,
    const float* __restrict__ scale, ushort* __restrict__ C, int M) {
  constexpr int BM = 128, BN = 128, KTOT = 256, BK = 64, WM = 2, WN = 2;
  constexpr int FM = (BM / WM) / 16;   // 4
  constexpr int FN = (BN / WN) / 16;   // 4
  constexpr int ABYTES = BM * BK * 2;  // 16 KB
  constexpr int BBYTES = BN * BK * 2;  // 16 KB
  __shared__ char lds[ABYTES + BBYTES];
  char* Asm = lds;
  char* Bsm = lds + ABYTES;

  const int tid = threadIdx.x;
  const int lane = tid & 63;
  const int w = tid >> 6;
  const int wm = w / WN, wn = w % WN;
  const int m0 = blockIdx.x * BM;

  f32x4 acc[FM][FN];
#pragma unroll
  for (int m = 0; m < FM; ++m)
#pragma unroll
    for (int n = 0; n < FN; ++n) acc[m][n] = (f32x4){0.f, 0.f, 0.f, 0.f};

  const int ra = lane & 15;
  const int kg = lane >> 4;

  float4 pfa[8];
#pragma unroll
  for (int s = 0; s < 4; ++s) {
    int L = s * 4096 + tid * 16;
    int r = L >> 7;
    int slot = (L >> 4) & 7;
    int gr = m0 + r; if (gr >= M) gr = M - 1;
    const float4* gp = (const float4*)(A + (size_t)gr * KTOT + slot * 8);
    pfa[2 * s] = gp[0];
    pfa[2 * s + 1] = gp[1];
  }

  for (int kt = 0; kt < KTOT / BK; ++kt) {
#pragma unroll
    for (int s = 0; s < 4; ++s) {
      int L = s * 4096 + tid * 16;
      int r = L >> 7;
      float4 va = pfa[2 * s], vb = pfa[2 * s + 1];
      bf16x8 o;
      o[0] = (short)f2bf(va.x); o[1] = (short)f2bf(va.y);
      o[2] = (short)f2bf(va.z); o[3] = (short)f2bf(va.w);
      o[4] = (short)f2bf(vb.x); o[5] = (short)f2bf(vb.y);
      o[6] = (short)f2bf(vb.z); o[7] = (short)f2bf(vb.w);
      *(bf16x8*)(Asm + (L ^ ((r & 7) << 4))) = o;
    }
#pragma unroll
    for (int s = 0; s < BBYTES / 4096; ++s) {
      int L = s * 4096 + tid * 16;
      int r = L >> 7;
      int slot = (L >> 4) & 7;
      const char* gp = (const char*)BT + (size_t)r * (KTOT * 2) + kt * (BK * 2)
                     + ((slot * 16) ^ ((r & 7) << 4));
      __builtin_amdgcn_global_load_lds(
          (const __attribute__((address_space(1))) unsigned*)gp,
          (__attribute__((address_space(3))) unsigned*)(Bsm + L), 16, 0, 0);
    }
    if (kt + 1 < KTOT / BK) {
#pragma unroll
      for (int s = 0; s < 4; ++s) {
        int L = s * 4096 + tid * 16;
        int r = L >> 7;
        int slot = (L >> 4) & 7;
        int gr = m0 + r; if (gr >= M) gr = M - 1;
        const float4* gp = (const float4*)(A + (size_t)gr * KTOT + (kt + 1) * BK + slot * 8);
        pfa[2 * s] = gp[0];
        pfa[2 * s + 1] = gp[1];
      }
    }
    __syncthreads();

#pragma unroll
    for (int ks = 0; ks < 2; ++ks) {
      bf16x8 af[FM], bfr[FN];
#pragma unroll
      for (int m = 0; m < FM; ++m) {
        int r = wm * (BM / WM) + m * 16 + ra;
        int cb = ks * 64 + kg * 16;
        af[m] = *(const bf16x8*)(Asm + r * 128 + (cb ^ ((r & 7) << 4)));
      }
#pragma unroll
      for (int n = 0; n < FN; ++n) {
        int c = wn * (BN / WN) + n * 16 + ra;
        int cb = ks * 64 + kg * 16;
        bfr[n] = *(const bf16x8*)(Bsm + c * 128 + (cb ^ ((c & 7) << 4)));
      }
#pragma unroll
      for (int m = 0; m < FM; ++m)
#pragma unroll
        for (int n = 0; n < FN; ++n)
          acc[m][n] = __builtin_amdgcn_mfma_f32_16x16x32_bf16(af[m], bfr[n], acc[m][n], 0, 0, 0);
    }
    __syncthreads();
  }

#pragma unroll
  for (int m = 0; m < FM; ++m) {
#pragma unroll
    for (int j = 0; j < 4; ++j) {
      int rl = wm * (BM / WM) + m * 16 + (lane >> 4) * 4 + j;
      int gr = m0 + rl;
      if (gr < M) {
        float sc = scale[gr];
#pragma unroll
        for (int n = 0; n < FN; ++n) {
          int c = wn * (BN / WN) + n * 16 + (lane & 15);
          C[(size_t)gr * BN + c] = f2bf(acc[m][n][j] * sc);
        }
      }
    }
  }
}

// ---------------- layer-2 GEMM (bf16 A via global_load_lds) ----------------
template<int BM, int BN, int KTOT, int WM, int WN>
__global__ __launch_bounds__(256) void mfma_gemm_scale(
    const ushort* __restrict__ A, const ushort* __restrict__ BT,
    const float* __restrict__ scale, ushort* __restrict__ C, int M) {
  constexpr int BK = 64;
  constexpr int FM = (BM / WM) / 16;
  constexpr int FN = (BN / WN) / 16;
  constexpr int ABYTES = BM * BK * 2;
  constexpr int BBYTES = BN * BK * 2;
  __shared__ char lds[ABYTES + BBYTES];
  char* Asm = lds;
  char* Bsm = lds + ABYTES;

  const int tid = threadIdx.x;
  const int lane = tid & 63;
  const int w = tid >> 6;
  const int wm = w / WN, wn = w % WN;
  const int m0 = blockIdx.x * BM;

  f32x4 acc[FM][FN];
#pragma unroll
  for (int m = 0; m < FM; ++m)
#pragma unroll
    for (int n = 0; n < FN; ++n) acc[m][n] = (f32x4){0.f, 0.f, 0.f, 0.f};

  const int ra = lane & 15;
  const int kg = lane >> 4;

  for (int kt = 0; kt < KTOT / BK; ++kt) {
#pragma unroll
    for (int s = 0; s < ABYTES / 4096; ++s) {
      int L = s * 4096 + tid * 16;
      int r = L >> 7;
      int slot = (L >> 4) & 7;
      int gr = m0 + r; if (gr >= M) gr = M - 1;
      const char* gp = (const char*)A + (size_t)gr * (KTOT * 2) + kt * (BK * 2)
                     + ((slot * 16) ^ ((r & 7) << 4));
      __builtin_amdgcn_global_load_lds(
          (const __attribute__((address_space(1))) unsigned*)gp,
          (__attribute__((address_space(3))) unsigned*)(Asm + L), 16, 0, 0);
    }
#pragma unroll
    for (int s = 0; s < BBYTES / 4096; ++s) {
      int L = s * 4096 + tid * 16;
      int r = L >> 7;
      int slot = (L >> 4) & 7;
      const char* gp = (const char*)BT + (size_t)r * (KTOT * 2) + kt * (BK * 2)
                     + ((slot * 16) ^ ((r & 7) << 4));
      __builtin_amdgcn_global_load_lds(
          (const __attribute__((address_space(1))) unsigned*)gp,
          (__attribute__((address_space(3))) unsigned*)(Bsm + L), 16, 0, 0);
    }
    __syncthreads();

#pragma unroll
    for (int ks = 0; ks < 2; ++ks) {
      bf16x8 af[FM], bfr[FN];
#pragma unroll
      for (int m = 0; m < FM; ++m) {
        int r = wm * (BM / WM) + m * 16 + ra;
        int cb = ks * 64 + kg * 16;
        af[m] = *(const bf16x8*)(Asm + r * 128 + (cb ^ ((r & 7) << 4)));
      }
#pragma unroll
      for (int n = 0; n < FN; ++n) {
        int c = wn * (BN / WN) + n * 16 + ra;
        int cb = ks * 64 + kg * 16;
        bfr[n] = *(const bf16x8*)(Bsm + c * 128 + (cb ^ ((c & 7) << 4)));
      }
#pragma unroll
      for (int m = 0; m < FM; ++m)
#pragma unroll
        for (int n = 0; n < FN; ++n)
          acc[m][n] = __builtin_amdgcn_mfma_f32_16x16x32_bf16(af[m], bfr[n], acc[m][n], 0, 0, 0);
    }
    __syncthreads();
  }

#pragma unroll
  for (int m = 0; m < FM; ++m) {
#pragma unroll
    for (int j = 0; j < 4; ++j) {
      int rl = wm * (BM / WM) + m * 16 + (lane >> 4) * 4 + j;
      int gr = m0 + rl;
      if (gr < M) {
        float sc = scale[gr];
#pragma unroll
        for (int n = 0; n < FN; ++n) {
          int c = wn * (BN / WN) + n * 16 + (lane & 15);
          C[(size_t)gr * BN + c] = f2bf(acc[m][n][j] * sc);
        }
      }
    }
  }
}

// ---------------- gather1 (1 node/wave, 16-deep MLP unroll) ----------------
__global__ void gather1(const ushort* __restrict__ h1, const int* __restrict__ off,
                        const int* __restrict__ csr, const float* __restrict__ nd,
                        const float* __restrict__ b1, ushort* __restrict__ x2, int N) {
  int w = (blockIdx.x * blockDim.x + threadIdx.x) >> 6;
  int lane = threadIdx.x & 63;
  if (w >= N) return;
  int lo = off[w], hi = off[w + 1];
  const unsigned* h = (const unsigned*)h1;
  float sx = 0.f, sy = 0.f;
#define ACC1(u) { sx += __builtin_bit_cast(float, (u) << 16); \
                  sy += __builtin_bit_cast(float, (u) & 0xFFFF0000u); }
  int j = lo;
  for (; j + 16 <= hi; j += 16) {
    int s0 = csr[j+0], s1 = csr[j+1], s2 = csr[j+2], s3 = csr[j+3];
    int s4 = csr[j+4], s5 = csr[j+5], s6 = csr[j+6], s7 = csr[j+7];
    int s8 = csr[j+8], s9 = csr[j+9], sa = csr[j+10], sb = csr[j+11];
    int sc_ = csr[j+12], sd = csr[j+13], se = csr[j+14], sf = csr[j+15];
    unsigned u0 = h[(size_t)s0 * 64 + lane];
    unsigned u1 = h[(size_t)s1 * 64 + lane];
    unsigned u2 = h[(size_t)s2 * 64 + lane];
    unsigned u3 = h[(size_t)s3 * 64 + lane];
    unsigned u4 = h[(size_t)s4 * 64 + lane];
    unsigned u5 = h[(size_t)s5 * 64 + lane];
    unsigned u6 = h[(size_t)s6 * 64 + lane];
    unsigned u7 = h[(size_t)s7 * 64 + lane];
    unsigned u8 = h[(size_t)s8 * 64 + lane];
    unsigned u9 = h[(size_t)s9 * 64 + lane];
    unsigned ua = h[(size_t)sa * 64 + lane];
    unsigned ub = h[(size_t)sb * 64 + lane];
    unsigned uc = h[(size_t)sc_ * 64 + lane];
    unsigned ud = h[(size_t)sd * 64 + lane];
    unsigned ue = h[(size_t)se * 64 + lane];
    unsigned uf = h[(size_t)sf * 64 + lane];
    ACC1(u0) ACC1(u1) ACC1(u2) ACC1(u3) ACC1(u4) ACC1(u5) ACC1(u6) ACC1(u7)
    ACC1(u8) ACC1(u9) ACC1(ua) ACC1(ub) ACC1(uc) ACC1(ud) ACC1(ue) ACC1(uf)
  }
  for (; j + 4 <= hi; j += 4) {
    int s0 = csr[j+0], s1 = csr[j+1], s2 = csr[j+2], s3 = csr[j+3];
    unsigned u0 = h[(size_t)s0 * 64 + lane];
    unsigned u1 = h[(size_t)s1 * 64 + lane];
    unsigned u2 = h[(size_t)s2 * 64 + lane];
    unsigned u3 = h[(size_t)s3 * 64 + lane];
    ACC1(u0) ACC1(u1) ACC1(u2) ACC1(u3)
  }
  for (; j < hi; ++j) {
    int s = csr[j];
    unsigned u = h[(size_t)s * 64 + lane];
    ACC1(u)
  }
#undef ACC1
  float sc = nd[w];
  float2 bb = ((const float2*)b1)[lane];
  float ox = fmaxf(sx * sc + bb.x, 0.f);
  float oy = fmaxf(sy * sc + bb.y, 0.f);
  ushort2 o; o.x = f2bf(ox); o.y = f2bf(oy);
  ((ushort2*)x2)[(size_t)w * 64 + lane] = o;
}

// ---------------- gather2 (2 nodes/wave, 16-deep) ----------------
__global__ void gather2(const ushort* __restrict__ h2, const int* __restrict__ off,
                        const int* __restrict__ csr, const float* __restrict__ nd,
                        const float* __restrict__ b2, float* __restrict__ out, int N) {
  int wv = (blockIdx.x * blockDim.x + threadIdx.x) >> 6;
  int lane = threadIdx.x & 63;
  int grp = lane >> 5;
  int sub = lane & 31;
  int node = wv * 2 + grp;
  if (node >= N) return;
  int lo = off[node], hi = off[node + 1];
  const unsigned* h = (const unsigned*)h2;
  float s0f = 0.f, s1f = 0.f;
#define ACC2(u) { s0f += __builtin_bit_cast(float, (u) << 16); \
                  s1f += __builtin_bit_cast(float, (u) & 0xFFFF0000u); }
  int j = lo;
  for (; j + 16 <= hi; j += 16) {
    int i0 = csr[j+0], i1 = csr[j+1], i2 = csr[j+2], i3 = csr[j+3];
    int i4 = csr[j+4], i5 = csr[j+5], i6 = csr[j+6], i7 = csr[j+7];
    int i8 = csr[j+8], i9 = csr[j+9], ia = csr[j+10], ib = csr[j+11];
    int ic = csr[j+12], id = csr[j+13], ie = csr[j+14], if_ = csr[j+15];
    unsigned u0 = h[(size_t)i0 * 32 + sub];
    unsigned u1 = h[(size_t)i1 * 32 + sub];
    unsigned u2 = h[(size_t)i2 * 32 + sub];
    unsigned u3 = h[(size_t)i3 * 32 + sub];
    unsigned u4 = h[(size_t)i4 * 32 + sub];
    unsigned u5 = h[(size_t)i5 * 32 + sub];
    unsigned u6 = h[(size_t)i6 * 32 + sub];
    unsigned u7 = h[(size_t)i7 * 32 + sub];
    unsigned u8 = h[(size_t)i8 * 32 + sub];
    unsigned u9 = h[(size_t)i9 * 32 + sub];
    unsigned ua = h[(size_t)ia * 32 + sub];
    unsigned ub = h[(size_t)ib * 32 + sub];
    unsigned uc = h[(size_t)ic * 32 + sub];
    unsigned ud = h[(size_t)id * 32 + sub];
    unsigned ue = h[(size_t)ie * 32 + sub];
    unsigned uf = h[(size_t)if_ * 32 + sub];
    ACC2(u0) ACC2(u1) ACC2(u2) ACC2(u3) ACC2(u4) ACC2(u5) ACC2(u6) ACC2(u7)
    ACC2(u8) ACC2(u9) ACC2(ua) ACC2(ub) ACC2(uc) ACC2(ud) ACC2(ue) ACC2(uf)
  }
  for (; j + 4 <= hi; j += 4) {
    int i0 = csr[j+0], i1 = csr[j+1], i2 = csr[j+2], i3 = csr[j+3];
    unsigned u0 = h[(size_t)i0 * 32 + sub];
    unsigned u1 = h[(size_t)i1 * 32 + sub];
    unsigned u2 = h[(size_t)i2 * 32 + sub];
    unsigned u3 = h[(size_t)i3 * 32 + sub];
    ACC2(u0) ACC2(u1) ACC2(u2) ACC2(u3)
  }
  for (; j < hi; ++j) {
    int i0 = csr[j];
    unsigned u = h[(size_t)i0 * 32 + sub];
    ACC2(u)
  }
#undef ACC2
  float scn = nd[node];
  float2 bb = ((const float2*)b2)[sub];
  float v0 = s0f * scn + bb.x;
  float v1 = s1f * scn + bb.y;
  float2 o;
  o.x = 1.f / (1.f + expf(-v0));
  o.y = 1.f / (1.f + expf(-v1));
  ((float2*)out)[(size_t)node * 32 + sub] = o;
}

extern "C" void kernel_launch(void* const* d_in, const int* in_sizes, int n_in,
                              void* d_out, int out_size, void* d_ws, size_t ws_size,
                              hipStream_t stream) {
  const float* feat = (const float*)d_in[0];
  const int*   src  = (const int*)d_in[1];
  const int*   dst  = (const int*)d_in[2];
  const float* W1   = (const float*)d_in[3];
  const float* b1   = (const float*)d_in[4];
  const float* W2   = (const float*)d_in[5];
  const float* b2   = (const float*)d_in[6];
  float* out = (float*)d_out;

  const int N = in_sizes[0] / IN_F;   // 100000
  const int E = in_sizes[1];          // 1600000

  const int NBK  = (N + 255) >> 8;            // 391 coarse buckets
  const int NBLK = (E + EPB - 1) / EPB;       // 782 sort blocks
  const int HLEN = 2 * NBK * NBLK;
  const int WBLK = (IN_F * H_F + H_F * N_CLS + 255) / 256;   // weight-conv blocks

  size_t off = 0;
  auto alloc = [&](size_t bytes) -> void* {
    void* p = (char*)d_ws + off;
    off = (off + bytes + 255) & ~(size_t)255;
    return p;
  };
  int*    hist    = (int*)alloc((size_t)HLEN * 4);
  int*    P       = (int*)alloc((size_t)(HLEN + 1) * 4);
  int*    bsum    = (int*)alloc((size_t)1024 * 4);
  int*    pairs_pk= (int*)alloc((size_t)E * 4);
  int*    srcs_s  = (int*)alloc((size_t)E * 4);
  float*  norm_s  = (float*)alloc((size_t)N * 4);
  float*  norm_d  = (float*)alloc((size_t)N * 4);
  int*    row_off = (int*)alloc((size_t)(N + 1) * 4);
  int*    csr     = (int*)alloc((size_t)E * 4);
  ushort* w1t     = (ushort*)alloc((size_t)H_F * IN_F * 2);
  ushort* w2t     = (ushort*)alloc((size_t)N_CLS * H_F * 2);
  ushort* h1      = (ushort*)alloc((size_t)N * H_F * 2);
  ushort* x2bf    = (ushort*)alloc((size_t)N * H_F * 2);
  ushort* h2      = (ushort*)alloc((size_t)N * N_CLS * 2);
  (void)ws_size;

  // graph build (atomic-free) + weight conv fused into hist launch
  hist_conv_kernel<<<NBLK + WBLK, 256, 0, stream>>>(src, dst, hist, W1, w1t, W2, w2t,
                                                    NBK, NBLK, E);
  const int NBS = (HLEN + SCAN_CHUNK - 1) / SCAN_CHUNK;
  scan_part<<<NBS, 256, 0, stream>>>(hist, bsum, HLEN);
  scan_bsum<<<1, 1024, 0, stream>>>(bsum, NBS);
  scan_final<<<NBS, 256, 0, stream>>>(hist, bsum, P, HLEN, 2 * E);
  scatter_kernel<<<NBLK, 256, 0, stream>>>(src, dst, P, pairs_pk, srcs_s, NBK, NBLK, E);
  csr_outdeg_bucket<<<NBK, 256, 0, stream>>>(pairs_pk, srcs_s, P, row_off,
                                             norm_d, norm_s, csr, NBK, NBLK, N, E);

  // layer 1 (conv fused into GEMM A-stage, async staging)
  mfma_gemm1<<<(N + 127) / 128, 256, 0, stream>>>(feat, w1t, norm_s, h1, N);
  gather1<<<(N * 64 + 255) / 256, 256, 0, stream>>>(h1, row_off, csr, norm_d, b1, x2bf, N);

  // layer 2
  mfma_gemm_scale<128, 64, 128, 2, 2><<<(N + 127) / 128, 256, 0, stream>>>(
      x2bf, w2t, norm_s, h2, N);
  int pairs = (N + 1) / 2;
  gather2<<<(pairs * 64 + 255) / 256, 256, 0, stream>>>(h2, row_off, csr, norm_d, b2, out, N);
}